// Round 17
// baseline (495.205 us; speedup 1.0000x reference)
//
#include <hip/hip_runtime.h>
#include <math.h>

#define NIMG 800
#define T_DIM 128
#define N_DIM 100
#define D_DIM 256

typedef unsigned short ushort_t;
typedef unsigned int uint_t;
typedef __attribute__((ext_vector_type(8))) short short8;
typedef __attribute__((ext_vector_type(4))) float f32x4;

// REC_LO[t] = DEC_LO[15-t];  REC_HI[t] = DEC_LO[t] * (-1)^t
__constant__ float c_RL[16] = {
     0.05441584224308161,   0.3128715909144659,    0.6756307362980128,    0.5853546836548691,
    -0.015829105256023893, -0.2840155429624281,    0.00047248457399797254,0.128747426620186,
    -0.01736930100202211,  -0.04408825393106472,   0.013981027917015516,  0.008746094047015655,
    -0.00487035299301066,  -0.0003917403729959771, 0.0006754494059985568, -0.00011747678400228192
};
__constant__ float c_RH[16] = {
    -0.00011747678400228192,-0.0006754494059985568,-0.0003917403729959771, 0.00487035299301066,
     0.008746094047015655,  -0.013981027917015516, -0.04408825393106472,   0.01736930100202211,
     0.128747426620186,     -0.00047248457399797254,-0.2840155429624281,   0.015829105256023893,
     0.5853546836548691,    -0.6756307362980128,    0.3128715909144659,   -0.05441584224308161
};

__device__ inline ushort_t f2bf(float f) {
    uint_t u = __float_as_uint(f);
    uint_t r = (u + 0x7FFFu + ((u >> 16) & 1u)) >> 16;
    return (ushort_t)r;
}

__device__ inline float softthr(float x, float th) {
    float m = fabsf(x) - th;
    return (m > 0.f) ? copysignf(m, x) : 0.f;
}

// Build combined 11x11 inception kernel
__global__ void k_build_comb(const float* w0, const float* w1, const float* w2,
                             const float* w3, const float* w4, const float* w5,
                             const float* b0, const float* b1, const float* b2,
                             const float* b3, const float* b4, const float* b5,
                             float* comb)
{
    int t = threadIdx.x;
    const float* wp[6] = {w0, w1, w2, w3, w4, w5};
    if (t < 121) {
        int dy = t / 11 - 5, dx = t % 11 - 5;
        int ay = dy < 0 ? -dy : dy, ax = dx < 0 ? -dx : dx;
        int a = ay > ax ? ay : ax;
        float s = 0.f;
        for (int i = a; i < 6; ++i) {
            int k = 2 * i + 1;
            s += wp[i][(i + dy) * k + (i + dx)];
        }
        comb[t] = s * (1.0f / 6.0f);
    } else if (t == 121) {
        comb[121] = (b0[0] + b1[0] + b2[0] + b3[0] + b4[0] + b5[0]) * (1.0f / 6.0f);
    }
}

__global__ void k_cvt_bf16(const float* __restrict__ in, ushort_t* __restrict__ out, int n)
{
    int i = blockIdx.x * blockDim.x + threadIdx.x;
    if (i < n) out[i] = f2bf(in[i]);
}

// Fused per-level 2D DWT v3: register-tiled passes, float2 staging, XCD swizzle.
// Parity offset 688 (=16 mod 32) -> even/odd pair hits banks 16 apart.
__global__ __launch_bounds__(256) void k_dwt2d_v3(const float* __restrict__ in,
    float* __restrict__ LL, float* __restrict__ LH,
    float* __restrict__ HL, float* __restrict__ HH,
    int H, int W, int nrb, int nstrips, int level0)
{
    __shared__ float xs[46 * 80];
    __shared__ float LpB[2 * 688];
    __shared__ float HpB[2 * 688];
    int h = H >> 1, w = W >> 1;
    int cpx = gridDim.x >> 3;
    int b0i = blockIdx.x;
    int bid = (b0i & 7) * cpx + (b0i >> 3);
    int per = nrb * nstrips;
    int img = bid / per;
    int rem = bid - img * per;
    int rb = rem / nstrips;
    int q = rem - rb * nstrips;
    int r0 = rb * 16, q0 = q * 32;
    int cb = 2 * q0 - 8;
    int jbase = 2 * r0 - 7;
    int tid = threadIdx.x;

    const float* ip; long rstride;
    if (level0) {
        int bb = img / 100, nn = img - bb * 100;
        ip = in + (long)bb * (T_DIM * N_DIM * D_DIM) + (long)nn * D_DIM;
        rstride = (long)N_DIM * D_DIM;
    } else {
        ip = in + (long)img * H * W;
        rstride = W;
    }

    for (int s = tid; s < 46 * 40; s += 256) {
        int jl = s / 40, k = s - jl * 40;
        int gj = jbase + jl, gc = cb + 2 * k;
        float2 v = make_float2(0.f, 0.f);
        if (gj >= 0 && gj < H && gc >= 0 && gc < W)
            v = *(const float2*)&ip[(long)gj * rstride + gc];
        *(float2*)&xs[jl * 80 + 2 * k] = v;
    }
    __syncthreads();

    for (int s = tid; s < 320; s += 256) {
        int g = s / 80, c = s - g * 80;
        float xv[22];
        const float* bp = xs + (8 * g) * 80 + c;
        #pragma unroll
        for (int k = 0; k < 22; ++k) xv[k] = bp[k * 80];
        #pragma unroll
        for (int o = 0; o < 4; ++o) {
            float sl = 0.f, sh = 0.f;
            #pragma unroll
            for (int t = 0; t < 16; ++t) {
                float v = xv[2 * o + t];
                sl = fmaf(c_RL[t], v, sl);
                sh = fmaf(c_RH[t], v, sh);
            }
            int il = 4 * g + o;
            int a = (c & 1) * 688 + il * 41 + (c >> 1);
            LpB[a] = sl;
            HpB[a] = sh;
        }
    }
    __syncthreads();

    {
        int rl = tid >> 4;
        int cp = tid & 15;
        int cl = cp * 2;
        float Lp0[10], Lp1[10], Hp0[10], Hp1[10];
        int base = rl * 41 + cl;
        #pragma unroll
        for (int k = 0; k < 10; ++k) {
            Lp0[k] = LpB[base + k];
            Lp1[k] = LpB[688 + base + k];
            Hp0[k] = HpB[base + k];
            Hp1[k] = HpB[688 + base + k];
        }
        float rll[2], rlh[2], rhl[2], rhh[2];
        #pragma unroll
        for (int n = 0; n < 2; ++n) {
            float ll = 0.f, lh = 0.f, hl = 0.f, hh = 0.f;
            #pragma unroll
            for (int t = 0; t < 16; ++t) {
                const int p = (t + 1) & 1;
                const int k = n + ((t + 1) >> 1);
                float av = p ? Lp1[k] : Lp0[k];
                float bv = p ? Hp1[k] : Hp0[k];
                ll = fmaf(c_RL[t], av, ll);
                lh = fmaf(c_RH[t], av, lh);
                hl = fmaf(c_RL[t], bv, hl);
                hh = fmaf(c_RH[t], bv, hh);
            }
            rll[n] = ll; rlh[n] = lh; rhl[n] = hl; rhh[n] = hh;
        }
        long o = (long)img * h * w + (long)(r0 + rl) * w + (q0 + cl);
        *(float2*)&LL[o] = make_float2(rll[0], rll[1]);
        *(float2*)&LH[o] = make_float2(rlh[0], rlh[1]);
        *(float2*)&HL[o] = make_float2(rhl[0], rhl[1]);
        *(float2*)&HH[o] = make_float2(rhh[0], rhh[1]);
    }
}

// Fused per-level 2D iDWT v4: 32-out-row tiles, float2 staging, XCD swizzle.
__global__ __launch_bounds__(256) void k_idwt2d_v4(const float* __restrict__ LLp,
    const float* __restrict__ LHp, const float* __restrict__ HLp,
    const float* __restrict__ HHp, float* __restrict__ outp,
    ushort_t* __restrict__ outbf, int H, int W, int nrb, int nstrips, int fin)
{
    __shared__ float subf[4][24][41];
    __shared__ float sLm[24 * 64];
    __shared__ float sHm[24 * 64];
    int h = H >> 1, w = W >> 1;
    int cpx = gridDim.x >> 3;
    int b0i = blockIdx.x;
    int bid = (b0i & 7) * cpx + (b0i >> 3);
    int per = nrb * nstrips;
    int img = bid / per;
    int rem = bid - img * per;
    int rb = rem / nstrips;
    int qs = rem - rb * nstrips;
    int j0 = rb * 32, q0 = qs * 64;
    int rbase = (j0 >> 1) - 4;
    int i0 = (q0 >> 1) - 4;
    int tid = threadIdx.x;
    long ibase = (long)img * h * w;

    for (int s = tid; s < 4 * 24 * 20; s += 256) {
        int b = s / 480;
        int r2 = s - b * 480;
        int r = r2 / 20, c2 = r2 - r * 20;
        int gr = rbase + r, gc = i0 + 2 * c2;
        float2 v = make_float2(0.f, 0.f);
        if (gr >= 0 && gr < h && gc >= 0 && gc < w) {
            const float* p = (b == 0) ? LLp : (b == 1) ? LHp : (b == 2) ? HLp : HHp;
            v = *(const float2*)&p[ibase + (long)gr * w + gc];
        }
        subf[b][r][2 * c2]     = v.x;
        subf[b][r][2 * c2 + 1] = v.y;
    }
    __syncthreads();

    for (int s = tid; s < 24 * 16; s += 256) {
        int r = s >> 4;
        int cg = s & 15;
        int lcb = cg * 2;
        float rs[4][10];
        #pragma unroll
        for (int b = 0; b < 4; ++b)
            #pragma unroll
            for (int k = 0; k < 10; ++k)
                rs[b][k] = subf[b][r][lcb + k];
        float accL[4], accH[4];
        #pragma unroll
        for (int n = 0; n < 4; ++n) {
            const int t0 = (n & 1) ? 0 : 1;
            const int kb = ((n & 1) ? 8 : 7) + (n >> 1);
            float aL = 0.f, aH = 0.f;
            #pragma unroll
            for (int tt = 0; tt < 8; ++tt) {
                const int t = t0 + 2 * tt;
                const int k = kb - tt;
                aL = fmaf(c_RL[t], rs[0][k], aL);
                aL = fmaf(c_RH[t], rs[1][k], aL);
                aH = fmaf(c_RL[t], rs[2][k], aH);
                aH = fmaf(c_RH[t], rs[3][k], aH);
            }
            accL[n] = aL; accH[n] = aH;
        }
        *(float4*)&sLm[r * 64 + cg * 4] = make_float4(accL[0], accL[1], accL[2], accL[3]);
        *(float4*)&sHm[r * 64 + cg * 4] = make_float4(accH[0], accH[1], accH[2], accH[3]);
    }
    __syncthreads();

    {
        int g = tid >> 6;
        int cl = tid & 63;
        float rL[12], rH[12];
        #pragma unroll
        for (int k = 0; k < 12; ++k) {
            rL[k] = sLm[(4 * g + k) * 64 + cl];
            rH[k] = sHm[(4 * g + k) * 64 + cl];
        }
        #pragma unroll
        for (int m = 0; m < 8; ++m) {
            const int t0 = (m & 1) ? 0 : 1;
            const int kb = ((m & 1) ? 8 : 7) + (m >> 1);
            float v = 0.f;
            #pragma unroll
            for (int tt = 0; tt < 8; ++tt) {
                const int t = t0 + 2 * tt;
                const int k = kb - tt;
                v = fmaf(c_RL[t], rL[k], v);
                v = fmaf(c_RH[t], rH[k], v);
            }
            int j = j0 + g * 8 + m;
            long o = (long)img * H * W + (long)j * W + q0 + cl;
            if (fin) outbf[o] = f2bf(v);
            else outp[o] = v;
        }
    }
}

// Bitonic-sort row median of |HH| (exact).
template<int W>
__global__ __launch_bounds__(256) void k_med_v2(const float* __restrict__ HH,
    float* __restrict__ thr, float scale)
{
    constexpr int R = 256 / W;
    __shared__ float smv[256];
    int tid = threadIdx.x;
    int l = tid % W;
    long row = (long)blockIdx.x * R + tid / W;
    float v = fabsf(HH[row * W + l]);
    #pragma unroll
    for (int k = 2; k <= W; k <<= 1) {
        #pragma unroll
        for (int j = k >> 1; j > 0; j >>= 1) {
            float pv;
            if (j < 64) {
                pv = __shfl_xor(v, j, 64);
            } else {
                smv[tid] = v;
                __syncthreads();
                pv = smv[tid ^ j];
                __syncthreads();
            }
            bool keepmin = ((l & k) == 0) == ((l & j) == 0);
            v = keepmin ? fminf(v, pv) : fmaxf(v, pv);
        }
    }
    if (l == (W - 1) / 2) thr[row] = v * scale;
}

// Register conv v9 (L0): full-image block (64 rows x 128 cols), thread = 4r x 8c.
// Mod-4 column-split LDS + row-stagger ((tr>>2)&1) -> conflict-free phases.
// Fused per-row soft-threshold on staging (tmul=0 for LL band).
#define PICK9(d) ( (d)==-5 ? f3[0] : (d)==-4 ? f0[0] : (d)==-3 ? f1[0] : \
                   (d)==-2 ? f2[0] : (d)==-1 ? f3[1] : (d)==0  ? f0[1] : \
                   (d)==1  ? f1[1] : (d)==2  ? f2[1] : (d)==3  ? f3[2] : \
                   (d)==4  ? f0[2] : (d)==5  ? f1[2] : (d)==6  ? f2[2] : \
                   (d)==7  ? f3[3] : (d)==8  ? f0[3] : (d)==9  ? f1[3] : \
                   (d)==10 ? f2[3] : (d)==11 ? f3[4] : (d)==12 ? f0[4] : f1[4] )
__global__ __launch_bounds__(256) void k_incept_v9(const float* __restrict__ bands,
    const float* __restrict__ thrp, const float* __restrict__ comb,
    float* __restrict__ oLL, float* __restrict__ oLH,
    float* __restrict__ oHL, float* __restrict__ oHH)
{
    constexpr int TR = 74;        // 64 + 10 halo rows
    constexpr int QP = 37;        // quarter pitch (36 used)
    constexpr int AS = TR * QP + 2;
    __shared__ float sm4[4 * AS];

    int cpx = gridDim.x >> 3;
    int b0i = blockIdx.x;
    int bid = (b0i & 7) * cpx + (b0i >> 3);
    int band = bid & 3;
    int img = bid >> 2;
    long S = (long)NIMG * 64 * 128;
    const float* in = bands + (long)band * S + (long)img * (64 * 128);
    float* outp = (band == 0 ? oLL : band == 1 ? oLH : band == 2 ? oHL : oHH)
                  + (long)img * (64 * 128);
    float tmul = (band == 0) ? 0.f : 1.f;
    const float* trow = thrp + (long)img * 64;
    int tid = threadIdx.x;

    // stage: tile row r <-> image row r-5; quarter q = qi-2 covers cols 4q..4q+3
    for (int s = tid; s < TR * 36; s += 256) {
        int r = s / 36, qi = s - r * 36;
        int q = qi - 2;
        int gr = r - 5;
        float4 v = make_float4(0.f, 0.f, 0.f, 0.f);
        if (gr >= 0 && gr < 64 && q >= 0 && q < 32) {
            v = *(const float4*)&in[(long)gr * 128 + 4 * q];
            float th = tmul * trow[gr];
            v.x = softthr(v.x, th);
            v.y = softthr(v.y, th);
            v.z = softthr(v.z, th);
            v.w = softthr(v.w, th);
        }
        int a = r * QP + ((r >> 2) & 1) + qi;
        sm4[0 * AS + a] = v.x;
        sm4[1 * AS + a] = v.y;
        sm4[2 * AS + a] = v.z;
        sm4[3 * AS + a] = v.w;
    }
    __syncthreads();

    int cg = tid & 15;       // col-group: 8 cols at x0 = 8*cg
    int rg = tid >> 4;       // row-group: 4 rows at rg*4
    float cb = comb[121];

    float acc[4][8];
    #pragma unroll
    for (int o = 0; o < 4; ++o)
        #pragma unroll
        for (int n = 0; n < 8; ++n) acc[o][n] = 0.f;

    #pragma unroll
    for (int i = 0; i < 14; ++i) {
        int tr = rg * 4 + i;
        int B = tr * QP + ((tr >> 2) & 1) + 2 * cg;   // qi base = 2cg (q=2cg-2)
        float f0[5], f1[5], f2[4], f3[5];
        #pragma unroll
        for (int j = 0; j < 5; ++j) f3[j] = sm4[3 * AS + B + j];
        #pragma unroll
        for (int j = 0; j < 5; ++j) f0[j] = sm4[0 * AS + B + 1 + j];
        #pragma unroll
        for (int j = 0; j < 5; ++j) f1[j] = sm4[1 * AS + B + 1 + j];
        #pragma unroll
        for (int j = 0; j < 4; ++j) f2[j] = sm4[2 * AS + B + 1 + j];
        #pragma unroll
        for (int ky = 0; ky < 11; ++ky) {
            const int o = i - ky;
            if (o >= 0 && o < 4) {
                #pragma unroll
                for (int kx = 0; kx < 11; ++kx) {
                    float cw = comb[ky * 11 + kx];
                    #pragma unroll
                    for (int n = 0; n < 8; ++n) {
                        const int d = n + kx - 5;
                        acc[o][n] = fmaf(PICK9(d), cw, acc[o][n]);
                    }
                }
            }
        }
    }

    #pragma unroll
    for (int o = 0; o < 4; ++o) {
        int oy = rg * 4 + o;
        float4 s0 = make_float4(acc[o][0] + cb, acc[o][1] + cb,
                                acc[o][2] + cb, acc[o][3] + cb);
        float4 s1 = make_float4(acc[o][4] + cb, acc[o][5] + cb,
                                acc[o][6] + cb, acc[o][7] + cb);
        *(float4*)&outp[(long)oy * 128 + 8 * cg] = s0;
        *(float4*)&outp[(long)oy * 128 + 8 * cg + 4] = s1;
    }
}

// Register conv v7 (L1/L2), fused soft-threshold on staging.
template<int WT, int BH, int OC, int NC>
__global__ __launch_bounds__(256) void k_incept_v7(const float* __restrict__ bands,
    const float* __restrict__ thrp, const float* __restrict__ comb,
    float* __restrict__ oLL, float* __restrict__ oLH,
    float* __restrict__ oHL, float* __restrict__ oHH)
{
    constexpr int Himg = WT / 2;
    constexpr int NRB = Himg / BH;
    constexpr int LW = WT / 2 + 6;
    constexpr int PITCH = WT / 2 + 7;
    constexpr int TR = BH + 10;
    constexpr int NB = WT / NC;
    __shared__ float smE[TR * PITCH + 1];
    __shared__ float smO[TR * PITCH + 1];

    int bid = blockIdx.x;
    int rb = (NRB > 1) ? (bid % NRB) : 0;
    int bi = (NRB > 1) ? (bid / NRB) : bid;
    int band = bi & 3;
    int img = bi >> 2;
    long S = (long)NIMG * Himg * WT;
    const float* in = bands + (long)band * S + (long)img * Himg * WT;
    float* outp = (band == 0 ? oLL : band == 1 ? oLH : band == 2 ? oHL : oHH)
                  + (long)img * Himg * WT;
    float tmul = (band == 0) ? 0.f : 1.f;
    const float* trow = thrp + (long)img * Himg;
    int r0 = rb * BH;
    int tid = threadIdx.x;

    for (int s = tid; s < TR * LW; s += 256) {
        int r = s / LW, j = s - r * LW;
        int c = j - 3;
        int gr = r0 - 5 + r;
        float2 v = make_float2(0.f, 0.f);
        if (gr >= 0 && gr < Himg && c >= 0 && c < WT / 2) {
            v = *(const float2*)&in[(long)gr * WT + 2 * c];
            float th = tmul * trow[gr];
            v.x = softthr(v.x, th);
            v.y = softthr(v.y, th);
        }
        int a = r * PITCH + ((r >> 2) & 1) + j;
        smE[a] = v.x;
        smO[a] = v.y;
    }
    __syncthreads();

    int cq = tid % NB;
    int rg = tid / NB;
    int x0 = cq * NC;
    float cb = comb[121];

    float acc[OC][NC];
    #pragma unroll
    for (int o = 0; o < OC; ++o)
        #pragma unroll
        for (int n = 0; n < NC; ++n) acc[o][n] = 0.f;

    float bufE[NC / 2 + 5], bufO[NC / 2 + 5];

    #pragma unroll
    for (int i = 0; i < OC + 10; ++i) {
        int tr = rg * OC + i;
        int base = tr * PITCH + ((tr >> 2) & 1) + (x0 >> 1);
        #pragma unroll
        for (int j = 0; j < NC / 2 + 5; ++j) {
            bufE[j] = smE[base + j + 1];
            bufO[j] = smO[base + j];
        }
        #pragma unroll
        for (int ky = 0; ky < 11; ++ky) {
            const int o = i - ky;
            if (o >= 0 && o < OC) {
                #pragma unroll
                for (int kx = 0; kx < 11; ++kx) {
                    float cw = comb[ky * 11 + kx];
                    #pragma unroll
                    for (int n = 0; n < NC; ++n) {
                        const int d = n + kx - 5;
                        float v = ((d & 1) == 0) ? bufE[(d + 4) / 2] : bufO[(d + 5) / 2];
                        acc[o][n] = fmaf(v, cw, acc[o][n]);
                    }
                }
            }
        }
    }

    #pragma unroll
    for (int o = 0; o < OC; ++o) {
        int oy = r0 + rg * OC + o;
        float2 st = make_float2(acc[o][0] + cb, acc[o][1] + cb);
        *(float2*)&outp[(long)oy * WT + x0] = st;
    }
}

// bf16 MFMA GEMM: out[m,d] = sum_k A[m,k]*W[d,k] + bias[d], scattered output.
__global__ __launch_bounds__(256) void k_gemm_bf16(const ushort_t* __restrict__ A,
    const ushort_t* __restrict__ Bw, const float* __restrict__ bias,
    float* __restrict__ out)
{
    __shared__ uint4 Al4[128 * 8];
    __shared__ uint4 Bl4[128 * 8];
    int m0 = blockIdx.x * 128, n0 = blockIdx.y * 128;
    int tid = threadIdx.x;
    int wid = tid >> 6, lane = tid & 63;
    int wr = wid >> 1, wc = wid & 1;
    f32x4 acc[4][4];
    #pragma unroll
    for (int a = 0; a < 4; ++a)
        #pragma unroll
        for (int b = 0; b < 4; ++b)
            acc[a][b] = (f32x4){0.f, 0.f, 0.f, 0.f};

    const uint4* Ag = (const uint4*)A;
    const uint4* Bg = (const uint4*)Bw;
    int row = tid >> 1, half = tid & 1;

    for (int k0 = 0; k0 < 256; k0 += 64) {
        int gca = ((m0 + row) * 256 + k0 + half * 32) >> 3;
        int gcb = ((n0 + row) * 256 + k0 + half * 32) >> 3;
        #pragma unroll
        for (int q = 0; q < 4; ++q) {
            int c = half * 4 + q;
            int sw = c ^ (row & 7);
            Al4[row * 8 + sw] = Ag[gca + q];
            Bl4[row * 8 + sw] = Bg[gcb + q];
        }
        __syncthreads();
        #pragma unroll
        for (int ks = 0; ks < 2; ++ks) {
            short8 af[4], bfr[4];
            int kc = ks * 4 + (lane >> 4);
            #pragma unroll
            for (int mi = 0; mi < 4; ++mi) {
                int r = wr * 64 + mi * 16 + (lane & 15);
                af[mi] = *(const short8*)&Al4[r * 8 + (kc ^ (r & 7))];
            }
            #pragma unroll
            for (int ni = 0; ni < 4; ++ni) {
                int r = wc * 64 + ni * 16 + (lane & 15);
                bfr[ni] = *(const short8*)&Bl4[r * 8 + (kc ^ (r & 7))];
            }
            #pragma unroll
            for (int mi = 0; mi < 4; ++mi)
                #pragma unroll
                for (int ni = 0; ni < 4; ++ni)
                    acc[mi][ni] = __builtin_amdgcn_mfma_f32_16x16x32_bf16(
                        af[mi], bfr[ni], acc[mi][ni], 0, 0, 0);
        }
        __syncthreads();
    }

    #pragma unroll
    for (int ni = 0; ni < 4; ++ni) {
        int d = n0 + wc * 64 + ni * 16 + (lane & 15);
        float bv = bias[d];
        #pragma unroll
        for (int mi = 0; mi < 4; ++mi) {
            #pragma unroll
            for (int r = 0; r < 4; ++r) {
                int m = m0 + wr * 64 + mi * 16 + (lane >> 4) * 4 + r;
                int img = m >> 7, t = m & 127;
                int bb = img / 100, nn = img - bb * 100;
                long ob = (((long)bb * T_DIM + t) * N_DIM + nn) * D_DIM + d;
                out[ob] = acc[mi][ni][r] + bv;
            }
        }
    }
}

extern "C" void kernel_launch(void* const* d_in, const int* in_sizes, int n_in,
                              void* d_out, int out_size, void* d_ws, size_t ws_size,
                              hipStream_t stream)
{
    const float* x = (const float*)d_in[0];
    const float* w0 = (const float*)d_in[2];  const float* b0 = (const float*)d_in[3];
    const float* w1 = (const float*)d_in[4];  const float* b1 = (const float*)d_in[5];
    const float* w2 = (const float*)d_in[6];  const float* b2 = (const float*)d_in[7];
    const float* w3 = (const float*)d_in[8];  const float* b3 = (const float*)d_in[9];
    const float* w4 = (const float*)d_in[10]; const float* b4 = (const float*)d_in[11];
    const float* w5 = (const float*)d_in[12]; const float* b5 = (const float*)d_in[13];
    const float* out_w = (const float*)d_in[14];
    const float* out_b = (const float*)d_in[15];
    float* ws = (float*)d_ws;
    float* outp = (float*)d_out;

    const long S0 = 6553600, S1 = 1638400, S2 = 409600;
    const long RT = 13107200;

    float* pLH[3] = { ws,               ws + 3 * S0,           ws + 3 * S0 + 3 * S1 };
    float* pHL[3] = { ws + S0,          ws + 3 * S0 + S1,      ws + 3 * S0 + 3 * S1 + S2 };
    float* pHH[3] = { ws + 2 * S0,      ws + 3 * S0 + 2 * S1,  ws + 3 * S0 + 3 * S1 + 2 * S2 };
    float* pLL2 = ws + 3 * S0 + 3 * S1 + 3 * S2;
    float* comb = ws + 3 * S0 + 3 * S1 + 4 * S2;
    float* thr  = comb + 128;
    float* wbf_f = thr + 51200;
    float* LLa  = wbf_f + 32768;
    float* LLb  = LLa + S0;
    float* bufA = LLb + S1;
    float* bufLL = bufA + RT;            // subband scratch + idwt outputs
    ushort_t* wbf = (ushort_t*)wbf_f;
    ushort_t* Abf = (ushort_t*)bufA;     // final idwt output (bf16), 52 MB
    float* idwt_out2 = bufLL;            // 800*32*64
    float* idwt_out1 = bufLL + S2 * 4;   // 800*64*128
    (void)ws_size; (void)in_sizes; (void)n_in; (void)out_size;

    hipLaunchKernelGGL(k_build_comb, dim3(1), dim3(128), 0, stream,
                       w0, w1, w2, w3, w4, w5, b0, b1, b2, b3, b4, b5, comb);
    hipLaunchKernelGGL(k_cvt_bf16, dim3(256), dim3(256), 0, stream, out_w, wbf, 65536);

    float thr_scale = (float)(sqrt(2.0 * log(128.0)) / 0.6745);

    int Hs[3] = {128, 64, 32}, Ws3[3] = {256, 128, 64};
    const float* curLL = x;
    float* convLLout[3] = { LLa, LLb, pLL2 };

    for (int lev = 0; lev < 3; ++lev) {
        int H = Hs[lev], W = Ws3[lev], h = H >> 1, w = W >> 1;
        long S = (long)NIMG * h * w;
        float* rLL = bufLL;
        float* rLH = bufLL + S;
        float* rHL = bufLL + 2 * S;
        float* rHH = bufLL + 3 * S;
        int nrb = h / 16, nstrips = w / 32;
        if (nrb < 1) nrb = 1;
        if (nstrips < 1) nstrips = 1;
        hipLaunchKernelGGL(k_dwt2d_v3, dim3(NIMG * nrb * nstrips), dim3(256), 0, stream,
                           curLL, rLL, rLH, rHL, rHH,
                           H, W, nrb, nstrips, lev == 0 ? 1 : 0);
        long rows = (long)NIMG * h;
        if (lev == 0) {
            hipLaunchKernelGGL(k_med_v2<128>, dim3((int)(rows / 2)), dim3(256), 0, stream,
                               rHH, thr, thr_scale);
            hipLaunchKernelGGL(k_incept_v9, dim3(NIMG * 4), dim3(256), 0, stream,
                               rLL, thr, comb, convLLout[lev], pLH[lev], pHL[lev], pHH[lev]);
        } else if (lev == 1) {
            hipLaunchKernelGGL(k_med_v2<64>, dim3((int)(rows / 4)), dim3(256), 0, stream,
                               rHH, thr, thr_scale);
            hipLaunchKernelGGL((k_incept_v7<64, 32, 4, 2>), dim3(NIMG * 4), dim3(256), 0, stream,
                               rLL, thr, comb, convLLout[lev], pLH[lev], pHL[lev], pHH[lev]);
        } else {
            hipLaunchKernelGGL(k_med_v2<32>, dim3((int)(rows / 8)), dim3(256), 0, stream,
                               rHH, thr, thr_scale);
            hipLaunchKernelGGL((k_incept_v7<32, 16, 1, 2>), dim3(NIMG * 4), dim3(256), 0, stream,
                               rLL, thr, comb, convLLout[lev], pLH[lev], pHL[lev], pHH[lev]);
        }
        curLL = convLLout[lev];
    }

    // iDWT chain (fused, v4: 32-row tiles + XCD swizzle)
    hipLaunchKernelGGL(k_idwt2d_v4, dim3(NIMG * 1 * 1), dim3(256), 0, stream,
                       pLL2, pLH[2], pHL[2], pHH[2], idwt_out2, (ushort_t*)0,
                       32, 64, 1, 1, 0);
    hipLaunchKernelGGL(k_idwt2d_v4, dim3(NIMG * 2 * 2), dim3(256), 0, stream,
                       idwt_out2, pLH[1], pHL[1], pHH[1], idwt_out1, (ushort_t*)0,
                       64, 128, 2, 2, 0);
    hipLaunchKernelGGL(k_idwt2d_v4, dim3(NIMG * 4 * 4), dim3(256), 0, stream,
                       idwt_out1, pLH[0], pHL[0], pHH[0], (float*)0, Abf,
                       128, 256, 4, 4, 1);

    dim3 gg(102400 / 128, 2);
    hipLaunchKernelGGL(k_gemm_bf16, gg, dim3(256), 0, stream, Abf, wbf, out_b, outp);
}

// Round 18
// 449.916 us; speedup vs baseline: 1.1007x; 1.1007x over previous
//
#include <hip/hip_runtime.h>
#include <math.h>

#define NIMG 800
#define T_DIM 128
#define N_DIM 100
#define D_DIM 256

typedef unsigned short ushort_t;
typedef unsigned int uint_t;
typedef __attribute__((ext_vector_type(8))) short short8;
typedef __attribute__((ext_vector_type(4))) float f32x4;

// REC_LO[t] = DEC_LO[15-t];  REC_HI[t] = DEC_LO[t] * (-1)^t
__constant__ float c_RL[16] = {
     0.05441584224308161,   0.3128715909144659,    0.6756307362980128,    0.5853546836548691,
    -0.015829105256023893, -0.2840155429624281,    0.00047248457399797254,0.128747426620186,
    -0.01736930100202211,  -0.04408825393106472,   0.013981027917015516,  0.008746094047015655,
    -0.00487035299301066,  -0.0003917403729959771, 0.0006754494059985568, -0.00011747678400228192
};
__constant__ float c_RH[16] = {
    -0.00011747678400228192,-0.0006754494059985568,-0.0003917403729959771, 0.00487035299301066,
     0.008746094047015655,  -0.013981027917015516, -0.04408825393106472,   0.01736930100202211,
     0.128747426620186,     -0.00047248457399797254,-0.2840155429624281,   0.015829105256023893,
     0.5853546836548691,    -0.6756307362980128,    0.3128715909144659,   -0.05441584224308161
};

__device__ inline ushort_t f2bf(float f) {
    uint_t u = __float_as_uint(f);
    uint_t r = (u + 0x7FFFu + ((u >> 16) & 1u)) >> 16;
    return (ushort_t)r;
}

__device__ inline float softthr(float x, float th) {
    float m = fabsf(x) - th;
    return (m > 0.f) ? copysignf(m, x) : 0.f;
}

// Build combined 11x11 inception kernel
__global__ void k_build_comb(const float* w0, const float* w1, const float* w2,
                             const float* w3, const float* w4, const float* w5,
                             const float* b0, const float* b1, const float* b2,
                             const float* b3, const float* b4, const float* b5,
                             float* comb)
{
    int t = threadIdx.x;
    const float* wp[6] = {w0, w1, w2, w3, w4, w5};
    if (t < 121) {
        int dy = t / 11 - 5, dx = t % 11 - 5;
        int ay = dy < 0 ? -dy : dy, ax = dx < 0 ? -dx : dx;
        int a = ay > ax ? ay : ax;
        float s = 0.f;
        for (int i = a; i < 6; ++i) {
            int k = 2 * i + 1;
            s += wp[i][(i + dy) * k + (i + dx)];
        }
        comb[t] = s * (1.0f / 6.0f);
    } else if (t == 121) {
        comb[121] = (b0[0] + b1[0] + b2[0] + b3[0] + b4[0] + b5[0]) * (1.0f / 6.0f);
    }
}

__global__ void k_cvt_bf16(const float* __restrict__ in, ushort_t* __restrict__ out, int n)
{
    int i = blockIdx.x * blockDim.x + threadIdx.x;
    if (i < n) out[i] = f2bf(in[i]);
}

// Fused per-level 2D DWT v3: register-tiled passes, float2 staging, XCD swizzle.
// Parity offset 688 (=16 mod 32) -> even/odd pair hits banks 16 apart.
__global__ __launch_bounds__(256) void k_dwt2d_v3(const float* __restrict__ in,
    float* __restrict__ LL, float* __restrict__ LH,
    float* __restrict__ HL, float* __restrict__ HH,
    int H, int W, int nrb, int nstrips, int level0)
{
    __shared__ float xs[46 * 80];
    __shared__ float LpB[2 * 688];
    __shared__ float HpB[2 * 688];
    int h = H >> 1, w = W >> 1;
    int cpx = gridDim.x >> 3;
    int b0i = blockIdx.x;
    int bid = (b0i & 7) * cpx + (b0i >> 3);
    int per = nrb * nstrips;
    int img = bid / per;
    int rem = bid - img * per;
    int rb = rem / nstrips;
    int q = rem - rb * nstrips;
    int r0 = rb * 16, q0 = q * 32;
    int cb = 2 * q0 - 8;
    int jbase = 2 * r0 - 7;
    int tid = threadIdx.x;

    const float* ip; long rstride;
    if (level0) {
        int bb = img / 100, nn = img - bb * 100;
        ip = in + (long)bb * (T_DIM * N_DIM * D_DIM) + (long)nn * D_DIM;
        rstride = (long)N_DIM * D_DIM;
    } else {
        ip = in + (long)img * H * W;
        rstride = W;
    }

    for (int s = tid; s < 46 * 40; s += 256) {
        int jl = s / 40, k = s - jl * 40;
        int gj = jbase + jl, gc = cb + 2 * k;
        float2 v = make_float2(0.f, 0.f);
        if (gj >= 0 && gj < H && gc >= 0 && gc < W)
            v = *(const float2*)&ip[(long)gj * rstride + gc];
        *(float2*)&xs[jl * 80 + 2 * k] = v;
    }
    __syncthreads();

    for (int s = tid; s < 320; s += 256) {
        int g = s / 80, c = s - g * 80;
        float xv[22];
        const float* bp = xs + (8 * g) * 80 + c;
        #pragma unroll
        for (int k = 0; k < 22; ++k) xv[k] = bp[k * 80];
        #pragma unroll
        for (int o = 0; o < 4; ++o) {
            float sl = 0.f, sh = 0.f;
            #pragma unroll
            for (int t = 0; t < 16; ++t) {
                float v = xv[2 * o + t];
                sl = fmaf(c_RL[t], v, sl);
                sh = fmaf(c_RH[t], v, sh);
            }
            int il = 4 * g + o;
            int a = (c & 1) * 688 + il * 41 + (c >> 1);
            LpB[a] = sl;
            HpB[a] = sh;
        }
    }
    __syncthreads();

    {
        int rl = tid >> 4;
        int cp = tid & 15;
        int cl = cp * 2;
        float Lp0[10], Lp1[10], Hp0[10], Hp1[10];
        int base = rl * 41 + cl;
        #pragma unroll
        for (int k = 0; k < 10; ++k) {
            Lp0[k] = LpB[base + k];
            Lp1[k] = LpB[688 + base + k];
            Hp0[k] = HpB[base + k];
            Hp1[k] = HpB[688 + base + k];
        }
        float rll[2], rlh[2], rhl[2], rhh[2];
        #pragma unroll
        for (int n = 0; n < 2; ++n) {
            float ll = 0.f, lh = 0.f, hl = 0.f, hh = 0.f;
            #pragma unroll
            for (int t = 0; t < 16; ++t) {
                const int p = (t + 1) & 1;
                const int k = n + ((t + 1) >> 1);
                float av = p ? Lp1[k] : Lp0[k];
                float bv = p ? Hp1[k] : Hp0[k];
                ll = fmaf(c_RL[t], av, ll);
                lh = fmaf(c_RH[t], av, lh);
                hl = fmaf(c_RL[t], bv, hl);
                hh = fmaf(c_RH[t], bv, hh);
            }
            rll[n] = ll; rlh[n] = lh; rhl[n] = hl; rhh[n] = hh;
        }
        long o = (long)img * h * w + (long)(r0 + rl) * w + (q0 + cl);
        *(float2*)&LL[o] = make_float2(rll[0], rll[1]);
        *(float2*)&LH[o] = make_float2(rlh[0], rlh[1]);
        *(float2*)&HL[o] = make_float2(rhl[0], rhl[1]);
        *(float2*)&HH[o] = make_float2(rhh[0], rhh[1]);
    }
}

// Fused per-level 2D iDWT v4: 32-out-row tiles, float2 staging, XCD swizzle.
__global__ __launch_bounds__(256) void k_idwt2d_v4(const float* __restrict__ LLp,
    const float* __restrict__ LHp, const float* __restrict__ HLp,
    const float* __restrict__ HHp, float* __restrict__ outp,
    ushort_t* __restrict__ outbf, int H, int W, int nrb, int nstrips, int fin)
{
    __shared__ float subf[4][24][41];
    __shared__ float sLm[24 * 64];
    __shared__ float sHm[24 * 64];
    int h = H >> 1, w = W >> 1;
    int cpx = gridDim.x >> 3;
    int b0i = blockIdx.x;
    int bid = (b0i & 7) * cpx + (b0i >> 3);
    int per = nrb * nstrips;
    int img = bid / per;
    int rem = bid - img * per;
    int rb = rem / nstrips;
    int qs = rem - rb * nstrips;
    int j0 = rb * 32, q0 = qs * 64;
    int rbase = (j0 >> 1) - 4;
    int i0 = (q0 >> 1) - 4;
    int tid = threadIdx.x;
    long ibase = (long)img * h * w;

    for (int s = tid; s < 4 * 24 * 20; s += 256) {
        int b = s / 480;
        int r2 = s - b * 480;
        int r = r2 / 20, c2 = r2 - r * 20;
        int gr = rbase + r, gc = i0 + 2 * c2;
        float2 v = make_float2(0.f, 0.f);
        if (gr >= 0 && gr < h && gc >= 0 && gc < w) {
            const float* p = (b == 0) ? LLp : (b == 1) ? LHp : (b == 2) ? HLp : HHp;
            v = *(const float2*)&p[ibase + (long)gr * w + gc];
        }
        subf[b][r][2 * c2]     = v.x;
        subf[b][r][2 * c2 + 1] = v.y;
    }
    __syncthreads();

    for (int s = tid; s < 24 * 16; s += 256) {
        int r = s >> 4;
        int cg = s & 15;
        int lcb = cg * 2;
        float rs[4][10];
        #pragma unroll
        for (int b = 0; b < 4; ++b)
            #pragma unroll
            for (int k = 0; k < 10; ++k)
                rs[b][k] = subf[b][r][lcb + k];
        float accL[4], accH[4];
        #pragma unroll
        for (int n = 0; n < 4; ++n) {
            const int t0 = (n & 1) ? 0 : 1;
            const int kb = ((n & 1) ? 8 : 7) + (n >> 1);
            float aL = 0.f, aH = 0.f;
            #pragma unroll
            for (int tt = 0; tt < 8; ++tt) {
                const int t = t0 + 2 * tt;
                const int k = kb - tt;
                aL = fmaf(c_RL[t], rs[0][k], aL);
                aL = fmaf(c_RH[t], rs[1][k], aL);
                aH = fmaf(c_RL[t], rs[2][k], aH);
                aH = fmaf(c_RH[t], rs[3][k], aH);
            }
            accL[n] = aL; accH[n] = aH;
        }
        *(float4*)&sLm[r * 64 + cg * 4] = make_float4(accL[0], accL[1], accL[2], accL[3]);
        *(float4*)&sHm[r * 64 + cg * 4] = make_float4(accH[0], accH[1], accH[2], accH[3]);
    }
    __syncthreads();

    {
        int g = tid >> 6;
        int cl = tid & 63;
        float rL[12], rH[12];
        #pragma unroll
        for (int k = 0; k < 12; ++k) {
            rL[k] = sLm[(4 * g + k) * 64 + cl];
            rH[k] = sHm[(4 * g + k) * 64 + cl];
        }
        #pragma unroll
        for (int m = 0; m < 8; ++m) {
            const int t0 = (m & 1) ? 0 : 1;
            const int kb = ((m & 1) ? 8 : 7) + (m >> 1);
            float v = 0.f;
            #pragma unroll
            for (int tt = 0; tt < 8; ++tt) {
                const int t = t0 + 2 * tt;
                const int k = kb - tt;
                v = fmaf(c_RL[t], rL[k], v);
                v = fmaf(c_RH[t], rH[k], v);
            }
            int j = j0 + g * 8 + m;
            long o = (long)img * H * W + (long)j * W + q0 + cl;
            if (fin) outbf[o] = f2bf(v);
            else outp[o] = v;
        }
    }
}

// Bitonic-sort row median of |HH| (exact).
template<int W>
__global__ __launch_bounds__(256) void k_med_v2(const float* __restrict__ HH,
    float* __restrict__ thr, float scale)
{
    constexpr int R = 256 / W;
    __shared__ float smv[256];
    int tid = threadIdx.x;
    int l = tid % W;
    long row = (long)blockIdx.x * R + tid / W;
    float v = fabsf(HH[row * W + l]);
    #pragma unroll
    for (int k = 2; k <= W; k <<= 1) {
        #pragma unroll
        for (int j = k >> 1; j > 0; j >>= 1) {
            float pv;
            if (j < 64) {
                pv = __shfl_xor(v, j, 64);
            } else {
                smv[tid] = v;
                __syncthreads();
                pv = smv[tid ^ j];
                __syncthreads();
            }
            bool keepmin = ((l & k) == 0) == ((l & j) == 0);
            v = keepmin ? fminf(v, pv) : fmaxf(v, pv);
        }
    }
    if (l == (W - 1) / 2) thr[row] = v * scale;
}

// Register conv v8 (L0): mod-4 column-split LDS, conflict-free, XCD swizzle,
// fused per-row soft-threshold on staging (tmul=0 for LL band -> identity).
#define PICK(d) ( (d)==-5 ? f3[0] : (d)==-4 ? f0[0] : (d)==-3 ? f1[0] : \
                  (d)==-2 ? f2[0] : (d)==-1 ? f3[1] : (d)==0  ? f0[1] : \
                  (d)==1  ? f1[1] : (d)==2  ? f2[1] : (d)==3  ? f3[2] : \
                  (d)==4  ? f0[2] : (d)==5  ? f1[2] : (d)==6  ? f2[2] : \
                  (d)==7  ? f3[3] : f0[3] )
__global__ __launch_bounds__(256) void k_incept_v8(const float* __restrict__ bands,
    const float* __restrict__ thrp, const float* __restrict__ comb,
    float* __restrict__ oLL, float* __restrict__ oLH,
    float* __restrict__ oHL, float* __restrict__ oHH)
{
    constexpr int TR = 42;
    constexpr int QP = 37;
    constexpr int AS = TR * QP;
    __shared__ float sm4[4 * AS];

    int cpx = gridDim.x >> 3;
    int b0i = blockIdx.x;
    int bid = (b0i & 7) * cpx + (b0i >> 3);
    int rb = bid & 1;
    int bi = bid >> 1;
    int band = bi & 3;
    int img = bi >> 2;
    long S = (long)NIMG * 64 * 128;
    const float* in = bands + (long)band * S + (long)img * (64 * 128);
    float* outp = (band == 0 ? oLL : band == 1 ? oLH : band == 2 ? oHL : oHH)
                  + (long)img * (64 * 128);
    float tmul = (band == 0) ? 0.f : 1.f;
    const float* trow = thrp + (long)img * 64;
    int r0 = rb * 32;
    int tid = threadIdx.x;

    for (int s = tid; s < TR * 36; s += 256) {
        int r = s / 36, qi = s - r * 36;
        int q = qi - 2;
        int gr = r0 - 5 + r;
        float4 v = make_float4(0.f, 0.f, 0.f, 0.f);
        if (gr >= 0 && gr < 64 && q >= 0 && q < 32) {
            v = *(const float4*)&in[(long)gr * 128 + 4 * q];
            float th = tmul * trow[gr];
            v.x = softthr(v.x, th);
            v.y = softthr(v.y, th);
            v.z = softthr(v.z, th);
            v.w = softthr(v.w, th);
        }
        int a = r * QP + qi;
        sm4[0 * AS + a] = v.x;
        sm4[1 * AS + a] = v.y;
        sm4[2 * AS + a] = v.z;
        sm4[3 * AS + a] = v.w;
    }
    __syncthreads();

    int cq = tid & 31;
    int rg = tid >> 5;
    float cb = comb[121];

    float acc[4][4];
    #pragma unroll
    for (int o = 0; o < 4; ++o)
        #pragma unroll
        for (int n = 0; n < 4; ++n) acc[o][n] = 0.f;

    #pragma unroll
    for (int i = 0; i < 14; ++i) {
        int tr = rg * 4 + i;
        int base = tr * QP + cq + 2;
        float f0[4], f1[3], f2[3], f3[4];
        f3[0] = sm4[3 * AS + base - 2];
        f0[0] = sm4[0 * AS + base - 1];
        f1[0] = sm4[1 * AS + base - 1];
        f2[0] = sm4[2 * AS + base - 1];
        f3[1] = sm4[3 * AS + base - 1];
        f0[1] = sm4[0 * AS + base];
        f1[1] = sm4[1 * AS + base];
        f2[1] = sm4[2 * AS + base];
        f3[2] = sm4[3 * AS + base];
        f0[2] = sm4[0 * AS + base + 1];
        f1[2] = sm4[1 * AS + base + 1];
        f2[2] = sm4[2 * AS + base + 1];
        f3[3] = sm4[3 * AS + base + 1];
        f0[3] = sm4[0 * AS + base + 2];
        #pragma unroll
        for (int ky = 0; ky < 11; ++ky) {
            const int o = i - ky;
            if (o >= 0 && o < 4) {
                #pragma unroll
                for (int kx = 0; kx < 11; ++kx) {
                    float cw = comb[ky * 11 + kx];
                    #pragma unroll
                    for (int n = 0; n < 4; ++n) {
                        const int d = n + kx - 5;
                        acc[o][n] = fmaf(PICK(d), cw, acc[o][n]);
                    }
                }
            }
        }
    }

    #pragma unroll
    for (int o = 0; o < 4; ++o) {
        int oy = r0 + rg * 4 + o;
        float4 st = make_float4(acc[o][0] + cb, acc[o][1] + cb,
                                acc[o][2] + cb, acc[o][3] + cb);
        *(float4*)&outp[(long)oy * 128 + 4 * cq] = st;
    }
}

// Register conv v7 (L1/L2), fused soft-threshold on staging.
template<int WT, int BH, int OC, int NC>
__global__ __launch_bounds__(256) void k_incept_v7(const float* __restrict__ bands,
    const float* __restrict__ thrp, const float* __restrict__ comb,
    float* __restrict__ oLL, float* __restrict__ oLH,
    float* __restrict__ oHL, float* __restrict__ oHH)
{
    constexpr int Himg = WT / 2;
    constexpr int NRB = Himg / BH;
    constexpr int LW = WT / 2 + 6;
    constexpr int PITCH = WT / 2 + 7;
    constexpr int TR = BH + 10;
    constexpr int NB = WT / NC;
    __shared__ float smE[TR * PITCH + 1];
    __shared__ float smO[TR * PITCH + 1];

    int bid = blockIdx.x;
    int rb = (NRB > 1) ? (bid % NRB) : 0;
    int bi = (NRB > 1) ? (bid / NRB) : bid;
    int band = bi & 3;
    int img = bi >> 2;
    long S = (long)NIMG * Himg * WT;
    const float* in = bands + (long)band * S + (long)img * Himg * WT;
    float* outp = (band == 0 ? oLL : band == 1 ? oLH : band == 2 ? oHL : oHH)
                  + (long)img * Himg * WT;
    float tmul = (band == 0) ? 0.f : 1.f;
    const float* trow = thrp + (long)img * Himg;
    int r0 = rb * BH;
    int tid = threadIdx.x;

    for (int s = tid; s < TR * LW; s += 256) {
        int r = s / LW, j = s - r * LW;
        int c = j - 3;
        int gr = r0 - 5 + r;
        float2 v = make_float2(0.f, 0.f);
        if (gr >= 0 && gr < Himg && c >= 0 && c < WT / 2) {
            v = *(const float2*)&in[(long)gr * WT + 2 * c];
            float th = tmul * trow[gr];
            v.x = softthr(v.x, th);
            v.y = softthr(v.y, th);
        }
        int a = r * PITCH + ((r >> 2) & 1) + j;
        smE[a] = v.x;
        smO[a] = v.y;
    }
    __syncthreads();

    int cq = tid % NB;
    int rg = tid / NB;
    int x0 = cq * NC;
    float cb = comb[121];

    float acc[OC][NC];
    #pragma unroll
    for (int o = 0; o < OC; ++o)
        #pragma unroll
        for (int n = 0; n < NC; ++n) acc[o][n] = 0.f;

    float bufE[NC / 2 + 5], bufO[NC / 2 + 5];

    #pragma unroll
    for (int i = 0; i < OC + 10; ++i) {
        int tr = rg * OC + i;
        int base = tr * PITCH + ((tr >> 2) & 1) + (x0 >> 1);
        #pragma unroll
        for (int j = 0; j < NC / 2 + 5; ++j) {
            bufE[j] = smE[base + j + 1];
            bufO[j] = smO[base + j];
        }
        #pragma unroll
        for (int ky = 0; ky < 11; ++ky) {
            const int o = i - ky;
            if (o >= 0 && o < OC) {
                #pragma unroll
                for (int kx = 0; kx < 11; ++kx) {
                    float cw = comb[ky * 11 + kx];
                    #pragma unroll
                    for (int n = 0; n < NC; ++n) {
                        const int d = n + kx - 5;
                        float v = ((d & 1) == 0) ? bufE[(d + 4) / 2] : bufO[(d + 5) / 2];
                        acc[o][n] = fmaf(v, cw, acc[o][n]);
                    }
                }
            }
        }
    }

    #pragma unroll
    for (int o = 0; o < OC; ++o) {
        int oy = r0 + rg * OC + o;
        float2 st = make_float2(acc[o][0] + cb, acc[o][1] + cb);
        *(float2*)&outp[(long)oy * WT + x0] = st;
    }
}

// bf16 MFMA GEMM: out[m,d] = sum_k A[m,k]*W[d,k] + bias[d], scattered output.
__global__ __launch_bounds__(256) void k_gemm_bf16(const ushort_t* __restrict__ A,
    const ushort_t* __restrict__ Bw, const float* __restrict__ bias,
    float* __restrict__ out)
{
    __shared__ uint4 Al4[128 * 8];
    __shared__ uint4 Bl4[128 * 8];
    int m0 = blockIdx.x * 128, n0 = blockIdx.y * 128;
    int tid = threadIdx.x;
    int wid = tid >> 6, lane = tid & 63;
    int wr = wid >> 1, wc = wid & 1;
    f32x4 acc[4][4];
    #pragma unroll
    for (int a = 0; a < 4; ++a)
        #pragma unroll
        for (int b = 0; b < 4; ++b)
            acc[a][b] = (f32x4){0.f, 0.f, 0.f, 0.f};

    const uint4* Ag = (const uint4*)A;
    const uint4* Bg = (const uint4*)Bw;
    int row = tid >> 1, half = tid & 1;

    for (int k0 = 0; k0 < 256; k0 += 64) {
        int gca = ((m0 + row) * 256 + k0 + half * 32) >> 3;
        int gcb = ((n0 + row) * 256 + k0 + half * 32) >> 3;
        #pragma unroll
        for (int q = 0; q < 4; ++q) {
            int c = half * 4 + q;
            int sw = c ^ (row & 7);
            Al4[row * 8 + sw] = Ag[gca + q];
            Bl4[row * 8 + sw] = Bg[gcb + q];
        }
        __syncthreads();
        #pragma unroll
        for (int ks = 0; ks < 2; ++ks) {
            short8 af[4], bfr[4];
            int kc = ks * 4 + (lane >> 4);
            #pragma unroll
            for (int mi = 0; mi < 4; ++mi) {
                int r = wr * 64 + mi * 16 + (lane & 15);
                af[mi] = *(const short8*)&Al4[r * 8 + (kc ^ (r & 7))];
            }
            #pragma unroll
            for (int ni = 0; ni < 4; ++ni) {
                int r = wc * 64 + ni * 16 + (lane & 15);
                bfr[ni] = *(const short8*)&Bl4[r * 8 + (kc ^ (r & 7))];
            }
            #pragma unroll
            for (int mi = 0; mi < 4; ++mi)
                #pragma unroll
                for (int ni = 0; ni < 4; ++ni)
                    acc[mi][ni] = __builtin_amdgcn_mfma_f32_16x16x32_bf16(
                        af[mi], bfr[ni], acc[mi][ni], 0, 0, 0);
        }
        __syncthreads();
    }

    #pragma unroll
    for (int ni = 0; ni < 4; ++ni) {
        int d = n0 + wc * 64 + ni * 16 + (lane & 15);
        float bv = bias[d];
        #pragma unroll
        for (int mi = 0; mi < 4; ++mi) {
            #pragma unroll
            for (int r = 0; r < 4; ++r) {
                int m = m0 + wr * 64 + mi * 16 + (lane >> 4) * 4 + r;
                int img = m >> 7, t = m & 127;
                int bb = img / 100, nn = img - bb * 100;
                long ob = (((long)bb * T_DIM + t) * N_DIM + nn) * D_DIM + d;
                out[ob] = acc[mi][ni][r] + bv;
            }
        }
    }
}

extern "C" void kernel_launch(void* const* d_in, const int* in_sizes, int n_in,
                              void* d_out, int out_size, void* d_ws, size_t ws_size,
                              hipStream_t stream)
{
    const float* x = (const float*)d_in[0];
    const float* w0 = (const float*)d_in[2];  const float* b0 = (const float*)d_in[3];
    const float* w1 = (const float*)d_in[4];  const float* b1 = (const float*)d_in[5];
    const float* w2 = (const float*)d_in[6];  const float* b2 = (const float*)d_in[7];
    const float* w3 = (const float*)d_in[8];  const float* b3 = (const float*)d_in[9];
    const float* w4 = (const float*)d_in[10]; const float* b4 = (const float*)d_in[11];
    const float* w5 = (const float*)d_in[12]; const float* b5 = (const float*)d_in[13];
    const float* out_w = (const float*)d_in[14];
    const float* out_b = (const float*)d_in[15];
    float* ws = (float*)d_ws;
    float* outp = (float*)d_out;

    const long S0 = 6553600, S1 = 1638400, S2 = 409600;
    const long RT = 13107200;

    float* pLH[3] = { ws,               ws + 3 * S0,           ws + 3 * S0 + 3 * S1 };
    float* pHL[3] = { ws + S0,          ws + 3 * S0 + S1,      ws + 3 * S0 + 3 * S1 + S2 };
    float* pHH[3] = { ws + 2 * S0,      ws + 3 * S0 + 2 * S1,  ws + 3 * S0 + 3 * S1 + 2 * S2 };
    float* pLL2 = ws + 3 * S0 + 3 * S1 + 3 * S2;
    float* comb = ws + 3 * S0 + 3 * S1 + 4 * S2;
    float* thr  = comb + 128;
    float* wbf_f = thr + 51200;
    float* LLa  = wbf_f + 32768;
    float* LLb  = LLa + S0;
    float* bufA = LLb + S1;
    float* bufLL = bufA + RT;            // subband scratch + idwt outputs
    ushort_t* wbf = (ushort_t*)wbf_f;
    ushort_t* Abf = (ushort_t*)bufA;     // final idwt output (bf16), 52 MB
    float* idwt_out2 = bufLL;            // 800*32*64
    float* idwt_out1 = bufLL + S2 * 4;   // 800*64*128
    (void)ws_size; (void)in_sizes; (void)n_in; (void)out_size;

    hipLaunchKernelGGL(k_build_comb, dim3(1), dim3(128), 0, stream,
                       w0, w1, w2, w3, w4, w5, b0, b1, b2, b3, b4, b5, comb);
    hipLaunchKernelGGL(k_cvt_bf16, dim3(256), dim3(256), 0, stream, out_w, wbf, 65536);

    float thr_scale = (float)(sqrt(2.0 * log(128.0)) / 0.6745);

    int Hs[3] = {128, 64, 32}, Ws3[3] = {256, 128, 64};
    const float* curLL = x;
    float* convLLout[3] = { LLa, LLb, pLL2 };

    for (int lev = 0; lev < 3; ++lev) {
        int H = Hs[lev], W = Ws3[lev], h = H >> 1, w = W >> 1;
        long S = (long)NIMG * h * w;
        float* rLL = bufLL;
        float* rLH = bufLL + S;
        float* rHL = bufLL + 2 * S;
        float* rHH = bufLL + 3 * S;
        int nrb = h / 16, nstrips = w / 32;
        if (nrb < 1) nrb = 1;
        if (nstrips < 1) nstrips = 1;
        hipLaunchKernelGGL(k_dwt2d_v3, dim3(NIMG * nrb * nstrips), dim3(256), 0, stream,
                           curLL, rLL, rLH, rHL, rHH,
                           H, W, nrb, nstrips, lev == 0 ? 1 : 0);
        long rows = (long)NIMG * h;
        if (lev == 0) {
            hipLaunchKernelGGL(k_med_v2<128>, dim3((int)(rows / 2)), dim3(256), 0, stream,
                               rHH, thr, thr_scale);
            hipLaunchKernelGGL(k_incept_v8, dim3(NIMG * 4 * 2), dim3(256), 0, stream,
                               rLL, thr, comb, convLLout[lev], pLH[lev], pHL[lev], pHH[lev]);
        } else if (lev == 1) {
            hipLaunchKernelGGL(k_med_v2<64>, dim3((int)(rows / 4)), dim3(256), 0, stream,
                               rHH, thr, thr_scale);
            hipLaunchKernelGGL((k_incept_v7<64, 32, 4, 2>), dim3(NIMG * 4), dim3(256), 0, stream,
                               rLL, thr, comb, convLLout[lev], pLH[lev], pHL[lev], pHH[lev]);
        } else {
            hipLaunchKernelGGL(k_med_v2<32>, dim3((int)(rows / 8)), dim3(256), 0, stream,
                               rHH, thr, thr_scale);
            hipLaunchKernelGGL((k_incept_v7<32, 16, 1, 2>), dim3(NIMG * 4), dim3(256), 0, stream,
                               rLL, thr, comb, convLLout[lev], pLH[lev], pHL[lev], pHH[lev]);
        }
        curLL = convLLout[lev];
    }

    // iDWT chain (fused, v4: 32-row tiles + XCD swizzle)
    hipLaunchKernelGGL(k_idwt2d_v4, dim3(NIMG * 1 * 1), dim3(256), 0, stream,
                       pLL2, pLH[2], pHL[2], pHH[2], idwt_out2, (ushort_t*)0,
                       32, 64, 1, 1, 0);
    hipLaunchKernelGGL(k_idwt2d_v4, dim3(NIMG * 2 * 2), dim3(256), 0, stream,
                       idwt_out2, pLH[1], pHL[1], pHH[1], idwt_out1, (ushort_t*)0,
                       64, 128, 2, 2, 0);
    hipLaunchKernelGGL(k_idwt2d_v4, dim3(NIMG * 4 * 4), dim3(256), 0, stream,
                       idwt_out1, pLH[0], pHL[0], pHH[0], (float*)0, Abf,
                       128, 256, 4, 4, 1);

    dim3 gg(102400 / 128, 2);
    hipLaunchKernelGGL(k_gemm_bf16, gg, dim3(256), 0, stream, Abf, wbf, out_b, outp);
}

// Round 19
// 406.201 us; speedup vs baseline: 1.2191x; 1.1076x over previous
//
#include <hip/hip_runtime.h>
#include <math.h>

#define NIMG 800
#define T_DIM 128
#define N_DIM 100
#define D_DIM 256

typedef unsigned short ushort_t;
typedef unsigned int uint_t;
typedef __attribute__((ext_vector_type(8))) short short8;
typedef __attribute__((ext_vector_type(4))) float f32x4;

// REC_LO[t] = DEC_LO[15-t];  REC_HI[t] = DEC_LO[t] * (-1)^t
__constant__ float c_RL[16] = {
     0.05441584224308161,   0.3128715909144659,    0.6756307362980128,    0.5853546836548691,
    -0.015829105256023893, -0.2840155429624281,    0.00047248457399797254,0.128747426620186,
    -0.01736930100202211,  -0.04408825393106472,   0.013981027917015516,  0.008746094047015655,
    -0.00487035299301066,  -0.0003917403729959771, 0.0006754494059985568, -0.00011747678400228192
};
__constant__ float c_RH[16] = {
    -0.00011747678400228192,-0.0006754494059985568,-0.0003917403729959771, 0.00487035299301066,
     0.008746094047015655,  -0.013981027917015516, -0.04408825393106472,   0.01736930100202211,
     0.128747426620186,     -0.00047248457399797254,-0.2840155429624281,   0.015829105256023893,
     0.5853546836548691,    -0.6756307362980128,    0.3128715909144659,   -0.05441584224308161
};

__device__ inline ushort_t f2bf(float f) {
    uint_t u = __float_as_uint(f);
    uint_t r = (u + 0x7FFFu + ((u >> 16) & 1u)) >> 16;
    return (ushort_t)r;
}

__device__ inline float softthr(float x, float th) {
    float m = fabsf(x) - th;
    return (m > 0.f) ? copysignf(m, x) : 0.f;
}

// Build combined 11x11 inception kernel
__global__ void k_build_comb(const float* w0, const float* w1, const float* w2,
                             const float* w3, const float* w4, const float* w5,
                             const float* b0, const float* b1, const float* b2,
                             const float* b3, const float* b4, const float* b5,
                             float* comb)
{
    int t = threadIdx.x;
    const float* wp[6] = {w0, w1, w2, w3, w4, w5};
    if (t < 121) {
        int dy = t / 11 - 5, dx = t % 11 - 5;
        int ay = dy < 0 ? -dy : dy, ax = dx < 0 ? -dx : dx;
        int a = ay > ax ? ay : ax;
        float s = 0.f;
        for (int i = a; i < 6; ++i) {
            int k = 2 * i + 1;
            s += wp[i][(i + dy) * k + (i + dx)];
        }
        comb[t] = s * (1.0f / 6.0f);
    } else if (t == 121) {
        comb[121] = (b0[0] + b1[0] + b2[0] + b3[0] + b4[0] + b5[0]) * (1.0f / 6.0f);
    }
}

__global__ void k_cvt_bf16(const float* __restrict__ in, ushort_t* __restrict__ out, int n)
{
    int i = blockIdx.x * blockDim.x + threadIdx.x;
    if (i < n) out[i] = f2bf(in[i]);
}

// Fused per-level 2D DWT v3: register-tiled passes, float4 staging, XCD swizzle.
// Parity offset 688 (=16 mod 32) -> even/odd pair hits banks 16 apart.
__global__ __launch_bounds__(256) void k_dwt2d_v3(const float* __restrict__ in,
    float* __restrict__ LL, float* __restrict__ LH,
    float* __restrict__ HL, float* __restrict__ HH,
    int H, int W, int nrb, int nstrips, int level0)
{
    __shared__ float xs[46 * 80];
    __shared__ float LpB[2 * 688];
    __shared__ float HpB[2 * 688];
    int h = H >> 1, w = W >> 1;
    int cpx = gridDim.x >> 3;
    int b0i = blockIdx.x;
    int bid = (b0i & 7) * cpx + (b0i >> 3);
    int per = nrb * nstrips;
    int img = bid / per;
    int rem = bid - img * per;
    int rb = rem / nstrips;
    int q = rem - rb * nstrips;
    int r0 = rb * 16, q0 = q * 32;
    int cb = 2 * q0 - 8;
    int jbase = 2 * r0 - 7;
    int tid = threadIdx.x;

    const float* ip; long rstride;
    if (level0) {
        int bb = img / 100, nn = img - bb * 100;
        ip = in + (long)bb * (T_DIM * N_DIM * D_DIM) + (long)nn * D_DIM;
        rstride = (long)N_DIM * D_DIM;
    } else {
        ip = in + (long)img * H * W;
        rstride = W;
    }

    // stage 46 x 80 (cols cb..cb+79), float4 loads (quads aligned, never straddle)
    for (int s = tid; s < 46 * 20; s += 256) {
        int jl = s / 20, k = s - jl * 20;
        int gj = jbase + jl, gc = cb + 4 * k;
        float4 v = make_float4(0.f, 0.f, 0.f, 0.f);
        if (gj >= 0 && gj < H && gc >= 0 && gc < W)
            v = *(const float4*)&ip[(long)gj * rstride + gc];
        *(float4*)&xs[jl * 80 + 4 * k] = v;
    }
    __syncthreads();

    for (int s = tid; s < 320; s += 256) {
        int g = s / 80, c = s - g * 80;
        float xv[22];
        const float* bp = xs + (8 * g) * 80 + c;
        #pragma unroll
        for (int k = 0; k < 22; ++k) xv[k] = bp[k * 80];
        #pragma unroll
        for (int o = 0; o < 4; ++o) {
            float sl = 0.f, sh = 0.f;
            #pragma unroll
            for (int t = 0; t < 16; ++t) {
                float v = xv[2 * o + t];
                sl = fmaf(c_RL[t], v, sl);
                sh = fmaf(c_RH[t], v, sh);
            }
            int il = 4 * g + o;
            int a = (c & 1) * 688 + il * 41 + (c >> 1);
            LpB[a] = sl;
            HpB[a] = sh;
        }
    }
    __syncthreads();

    {
        int rl = tid >> 4;
        int cp = tid & 15;
        int cl = cp * 2;
        float Lp0[10], Lp1[10], Hp0[10], Hp1[10];
        int base = rl * 41 + cl;
        #pragma unroll
        for (int k = 0; k < 10; ++k) {
            Lp0[k] = LpB[base + k];
            Lp1[k] = LpB[688 + base + k];
            Hp0[k] = HpB[base + k];
            Hp1[k] = HpB[688 + base + k];
        }
        float rll[2], rlh[2], rhl[2], rhh[2];
        #pragma unroll
        for (int n = 0; n < 2; ++n) {
            float ll = 0.f, lh = 0.f, hl = 0.f, hh = 0.f;
            #pragma unroll
            for (int t = 0; t < 16; ++t) {
                const int p = (t + 1) & 1;
                const int k = n + ((t + 1) >> 1);
                float av = p ? Lp1[k] : Lp0[k];
                float bv = p ? Hp1[k] : Hp0[k];
                ll = fmaf(c_RL[t], av, ll);
                lh = fmaf(c_RH[t], av, lh);
                hl = fmaf(c_RL[t], bv, hl);
                hh = fmaf(c_RH[t], bv, hh);
            }
            rll[n] = ll; rlh[n] = lh; rhl[n] = hl; rhh[n] = hh;
        }
        long o = (long)img * h * w + (long)(r0 + rl) * w + (q0 + cl);
        *(float2*)&LL[o] = make_float2(rll[0], rll[1]);
        *(float2*)&LH[o] = make_float2(rlh[0], rlh[1]);
        *(float2*)&HL[o] = make_float2(rhl[0], rhl[1]);
        *(float2*)&HH[o] = make_float2(rhh[0], rhh[1]);
    }
}

// Fused per-level 2D iDWT v4: 32-out-row tiles, float4 staging, XCD swizzle.
__global__ __launch_bounds__(256) void k_idwt2d_v4(const float* __restrict__ LLp,
    const float* __restrict__ LHp, const float* __restrict__ HLp,
    const float* __restrict__ HHp, float* __restrict__ outp,
    ushort_t* __restrict__ outbf, int H, int W, int nrb, int nstrips, int fin)
{
    __shared__ float subf[4][24][41];
    __shared__ float sLm[24 * 64];
    __shared__ float sHm[24 * 64];
    int h = H >> 1, w = W >> 1;
    int cpx = gridDim.x >> 3;
    int b0i = blockIdx.x;
    int bid = (b0i & 7) * cpx + (b0i >> 3);
    int per = nrb * nstrips;
    int img = bid / per;
    int rem = bid - img * per;
    int rb = rem / nstrips;
    int qs = rem - rb * nstrips;
    int j0 = rb * 32, q0 = qs * 64;
    int rbase = (j0 >> 1) - 4;
    int i0 = (q0 >> 1) - 4;
    int tid = threadIdx.x;
    long ibase = (long)img * h * w;

    // stage 4 subband halo tiles (24 x 40, zero-padded), float4 loads
    for (int s = tid; s < 4 * 24 * 10; s += 256) {
        int b = s / 240;
        int r2 = s - b * 240;
        int r = r2 / 10, c4 = r2 - r * 10;
        int gr = rbase + r, gc = i0 + 4 * c4;
        float4 v = make_float4(0.f, 0.f, 0.f, 0.f);
        if (gr >= 0 && gr < h && gc >= 0 && gc < w) {
            const float* p = (b == 0) ? LLp : (b == 1) ? LHp : (b == 2) ? HLp : HHp;
            v = *(const float4*)&p[ibase + (long)gr * w + gc];
        }
        subf[b][r][4 * c4]     = v.x;
        subf[b][r][4 * c4 + 1] = v.y;
        subf[b][r][4 * c4 + 2] = v.z;
        subf[b][r][4 * c4 + 3] = v.w;
    }
    __syncthreads();

    for (int s = tid; s < 24 * 16; s += 256) {
        int r = s >> 4;
        int cg = s & 15;
        int lcb = cg * 2;
        float rs[4][10];
        #pragma unroll
        for (int b = 0; b < 4; ++b)
            #pragma unroll
            for (int k = 0; k < 10; ++k)
                rs[b][k] = subf[b][r][lcb + k];
        float accL[4], accH[4];
        #pragma unroll
        for (int n = 0; n < 4; ++n) {
            const int t0 = (n & 1) ? 0 : 1;
            const int kb = ((n & 1) ? 8 : 7) + (n >> 1);
            float aL = 0.f, aH = 0.f;
            #pragma unroll
            for (int tt = 0; tt < 8; ++tt) {
                const int t = t0 + 2 * tt;
                const int k = kb - tt;
                aL = fmaf(c_RL[t], rs[0][k], aL);
                aL = fmaf(c_RH[t], rs[1][k], aL);
                aH = fmaf(c_RL[t], rs[2][k], aH);
                aH = fmaf(c_RH[t], rs[3][k], aH);
            }
            accL[n] = aL; accH[n] = aH;
        }
        *(float4*)&sLm[r * 64 + cg * 4] = make_float4(accL[0], accL[1], accL[2], accL[3]);
        *(float4*)&sHm[r * 64 + cg * 4] = make_float4(accH[0], accH[1], accH[2], accH[3]);
    }
    __syncthreads();

    {
        int g = tid >> 6;
        int cl = tid & 63;
        float rL[12], rH[12];
        #pragma unroll
        for (int k = 0; k < 12; ++k) {
            rL[k] = sLm[(4 * g + k) * 64 + cl];
            rH[k] = sHm[(4 * g + k) * 64 + cl];
        }
        #pragma unroll
        for (int m = 0; m < 8; ++m) {
            const int t0 = (m & 1) ? 0 : 1;
            const int kb = ((m & 1) ? 8 : 7) + (m >> 1);
            float v = 0.f;
            #pragma unroll
            for (int tt = 0; tt < 8; ++tt) {
                const int t = t0 + 2 * tt;
                const int k = kb - tt;
                v = fmaf(c_RL[t], rL[k], v);
                v = fmaf(c_RH[t], rH[k], v);
            }
            int j = j0 + g * 8 + m;
            long o = (long)img * H * W + (long)j * W + q0 + cl;
            if (fin) outbf[o] = f2bf(v);
            else outp[o] = v;
        }
    }
}

// Bitonic-sort row median of |HH| (exact).
template<int W>
__global__ __launch_bounds__(256) void k_med_v2(const float* __restrict__ HH,
    float* __restrict__ thr, float scale)
{
    constexpr int R = 256 / W;
    __shared__ float smv[256];
    int tid = threadIdx.x;
    int l = tid % W;
    long row = (long)blockIdx.x * R + tid / W;
    float v = fabsf(HH[row * W + l]);
    #pragma unroll
    for (int k = 2; k <= W; k <<= 1) {
        #pragma unroll
        for (int j = k >> 1; j > 0; j >>= 1) {
            float pv;
            if (j < 64) {
                pv = __shfl_xor(v, j, 64);
            } else {
                smv[tid] = v;
                __syncthreads();
                pv = smv[tid ^ j];
                __syncthreads();
            }
            bool keepmin = ((l & k) == 0) == ((l & j) == 0);
            v = keepmin ? fminf(v, pv) : fmaxf(v, pv);
        }
    }
    if (l == (W - 1) / 2) thr[row] = v * scale;
}

// Register conv v8 (L0): mod-4 column-split LDS, conflict-free, XCD swizzle,
// fused per-row soft-threshold on staging (tmul=0 for LL band -> identity).
#define PICK(d) ( (d)==-5 ? f3[0] : (d)==-4 ? f0[0] : (d)==-3 ? f1[0] : \
                  (d)==-2 ? f2[0] : (d)==-1 ? f3[1] : (d)==0  ? f0[1] : \
                  (d)==1  ? f1[1] : (d)==2  ? f2[1] : (d)==3  ? f3[2] : \
                  (d)==4  ? f0[2] : (d)==5  ? f1[2] : (d)==6  ? f2[2] : \
                  (d)==7  ? f3[3] : f0[3] )
__global__ __launch_bounds__(256) void k_incept_v8(const float* __restrict__ bands,
    const float* __restrict__ thrp, const float* __restrict__ comb,
    float* __restrict__ oLL, float* __restrict__ oLH,
    float* __restrict__ oHL, float* __restrict__ oHH)
{
    constexpr int TR = 42;
    constexpr int QP = 37;
    constexpr int AS = TR * QP;
    __shared__ float sm4[4 * AS];

    int cpx = gridDim.x >> 3;
    int b0i = blockIdx.x;
    int bid = (b0i & 7) * cpx + (b0i >> 3);
    int rb = bid & 1;
    int bi = bid >> 1;
    int band = bi & 3;
    int img = bi >> 2;
    long S = (long)NIMG * 64 * 128;
    const float* in = bands + (long)band * S + (long)img * (64 * 128);
    float* outp = (band == 0 ? oLL : band == 1 ? oLH : band == 2 ? oHL : oHH)
                  + (long)img * (64 * 128);
    float tmul = (band == 0) ? 0.f : 1.f;
    const float* trow = thrp + (long)img * 64;
    int r0 = rb * 32;
    int tid = threadIdx.x;

    for (int s = tid; s < TR * 36; s += 256) {
        int r = s / 36, qi = s - r * 36;
        int q = qi - 2;
        int gr = r0 - 5 + r;
        float4 v = make_float4(0.f, 0.f, 0.f, 0.f);
        if (gr >= 0 && gr < 64 && q >= 0 && q < 32) {
            v = *(const float4*)&in[(long)gr * 128 + 4 * q];
            float th = tmul * trow[gr];
            v.x = softthr(v.x, th);
            v.y = softthr(v.y, th);
            v.z = softthr(v.z, th);
            v.w = softthr(v.w, th);
        }
        int a = r * QP + qi;
        sm4[0 * AS + a] = v.x;
        sm4[1 * AS + a] = v.y;
        sm4[2 * AS + a] = v.z;
        sm4[3 * AS + a] = v.w;
    }
    __syncthreads();

    int cq = tid & 31;
    int rg = tid >> 5;
    float cb = comb[121];

    float acc[4][4];
    #pragma unroll
    for (int o = 0; o < 4; ++o)
        #pragma unroll
        for (int n = 0; n < 4; ++n) acc[o][n] = 0.f;

    #pragma unroll
    for (int i = 0; i < 14; ++i) {
        int tr = rg * 4 + i;
        int base = tr * QP + cq + 2;
        float f0[4], f1[3], f2[3], f3[4];
        f3[0] = sm4[3 * AS + base - 2];
        f0[0] = sm4[0 * AS + base - 1];
        f1[0] = sm4[1 * AS + base - 1];
        f2[0] = sm4[2 * AS + base - 1];
        f3[1] = sm4[3 * AS + base - 1];
        f0[1] = sm4[0 * AS + base];
        f1[1] = sm4[1 * AS + base];
        f2[1] = sm4[2 * AS + base];
        f3[2] = sm4[3 * AS + base];
        f0[2] = sm4[0 * AS + base + 1];
        f1[2] = sm4[1 * AS + base + 1];
        f2[2] = sm4[2 * AS + base + 1];
        f3[3] = sm4[3 * AS + base + 1];
        f0[3] = sm4[0 * AS + base + 2];
        #pragma unroll
        for (int ky = 0; ky < 11; ++ky) {
            const int o = i - ky;
            if (o >= 0 && o < 4) {
                #pragma unroll
                for (int kx = 0; kx < 11; ++kx) {
                    float cw = comb[ky * 11 + kx];
                    #pragma unroll
                    for (int n = 0; n < 4; ++n) {
                        const int d = n + kx - 5;
                        acc[o][n] = fmaf(PICK(d), cw, acc[o][n]);
                    }
                }
            }
        }
    }

    #pragma unroll
    for (int o = 0; o < 4; ++o) {
        int oy = r0 + rg * 4 + o;
        float4 st = make_float4(acc[o][0] + cb, acc[o][1] + cb,
                                acc[o][2] + cb, acc[o][3] + cb);
        *(float4*)&outp[(long)oy * 128 + 4 * cq] = st;
    }
}

// Register conv v7 (L1/L2), fused soft-threshold on staging.
template<int WT, int BH, int OC, int NC>
__global__ __launch_bounds__(256) void k_incept_v7(const float* __restrict__ bands,
    const float* __restrict__ thrp, const float* __restrict__ comb,
    float* __restrict__ oLL, float* __restrict__ oLH,
    float* __restrict__ oHL, float* __restrict__ oHH)
{
    constexpr int Himg = WT / 2;
    constexpr int NRB = Himg / BH;
    constexpr int LW = WT / 2 + 6;
    constexpr int PITCH = WT / 2 + 7;
    constexpr int TR = BH + 10;
    constexpr int NB = WT / NC;
    __shared__ float smE[TR * PITCH + 1];
    __shared__ float smO[TR * PITCH + 1];

    int bid = blockIdx.x;
    int rb = (NRB > 1) ? (bid % NRB) : 0;
    int bi = (NRB > 1) ? (bid / NRB) : bid;
    int band = bi & 3;
    int img = bi >> 2;
    long S = (long)NIMG * Himg * WT;
    const float* in = bands + (long)band * S + (long)img * Himg * WT;
    float* outp = (band == 0 ? oLL : band == 1 ? oLH : band == 2 ? oHL : oHH)
                  + (long)img * Himg * WT;
    float tmul = (band == 0) ? 0.f : 1.f;
    const float* trow = thrp + (long)img * Himg;
    int r0 = rb * BH;
    int tid = threadIdx.x;

    for (int s = tid; s < TR * LW; s += 256) {
        int r = s / LW, j = s - r * LW;
        int c = j - 3;
        int gr = r0 - 5 + r;
        float2 v = make_float2(0.f, 0.f);
        if (gr >= 0 && gr < Himg && c >= 0 && c < WT / 2) {
            v = *(const float2*)&in[(long)gr * WT + 2 * c];
            float th = tmul * trow[gr];
            v.x = softthr(v.x, th);
            v.y = softthr(v.y, th);
        }
        int a = r * PITCH + ((r >> 2) & 1) + j;
        smE[a] = v.x;
        smO[a] = v.y;
    }
    __syncthreads();

    int cq = tid % NB;
    int rg = tid / NB;
    int x0 = cq * NC;
    float cb = comb[121];

    float acc[OC][NC];
    #pragma unroll
    for (int o = 0; o < OC; ++o)
        #pragma unroll
        for (int n = 0; n < NC; ++n) acc[o][n] = 0.f;

    float bufE[NC / 2 + 5], bufO[NC / 2 + 5];

    #pragma unroll
    for (int i = 0; i < OC + 10; ++i) {
        int tr = rg * OC + i;
        int base = tr * PITCH + ((tr >> 2) & 1) + (x0 >> 1);
        #pragma unroll
        for (int j = 0; j < NC / 2 + 5; ++j) {
            bufE[j] = smE[base + j + 1];
            bufO[j] = smO[base + j];
        }
        #pragma unroll
        for (int ky = 0; ky < 11; ++ky) {
            const int o = i - ky;
            if (o >= 0 && o < OC) {
                #pragma unroll
                for (int kx = 0; kx < 11; ++kx) {
                    float cw = comb[ky * 11 + kx];
                    #pragma unroll
                    for (int n = 0; n < NC; ++n) {
                        const int d = n + kx - 5;
                        float v = ((d & 1) == 0) ? bufE[(d + 4) / 2] : bufO[(d + 5) / 2];
                        acc[o][n] = fmaf(v, cw, acc[o][n]);
                    }
                }
            }
        }
    }

    #pragma unroll
    for (int o = 0; o < OC; ++o) {
        int oy = r0 + rg * OC + o;
        float2 st = make_float2(acc[o][0] + cb, acc[o][1] + cb);
        *(float2*)&outp[(long)oy * WT + x0] = st;
    }
}

// bf16 MFMA GEMM: out[m,d] = sum_k A[m,k]*W[d,k] + bias[d], scattered output.
__global__ __launch_bounds__(256) void k_gemm_bf16(const ushort_t* __restrict__ A,
    const ushort_t* __restrict__ Bw, const float* __restrict__ bias,
    float* __restrict__ out)
{
    __shared__ uint4 Al4[128 * 8];
    __shared__ uint4 Bl4[128 * 8];
    int m0 = blockIdx.x * 128, n0 = blockIdx.y * 128;
    int tid = threadIdx.x;
    int wid = tid >> 6, lane = tid & 63;
    int wr = wid >> 1, wc = wid & 1;
    f32x4 acc[4][4];
    #pragma unroll
    for (int a = 0; a < 4; ++a)
        #pragma unroll
        for (int b = 0; b < 4; ++b)
            acc[a][b] = (f32x4){0.f, 0.f, 0.f, 0.f};

    const uint4* Ag = (const uint4*)A;
    const uint4* Bg = (const uint4*)Bw;
    int row = tid >> 1, half = tid & 1;

    for (int k0 = 0; k0 < 256; k0 += 64) {
        int gca = ((m0 + row) * 256 + k0 + half * 32) >> 3;
        int gcb = ((n0 + row) * 256 + k0 + half * 32) >> 3;
        #pragma unroll
        for (int q = 0; q < 4; ++q) {
            int c = half * 4 + q;
            int sw = c ^ (row & 7);
            Al4[row * 8 + sw] = Ag[gca + q];
            Bl4[row * 8 + sw] = Bg[gcb + q];
        }
        __syncthreads();
        #pragma unroll
        for (int ks = 0; ks < 2; ++ks) {
            short8 af[4], bfr[4];
            int kc = ks * 4 + (lane >> 4);
            #pragma unroll
            for (int mi = 0; mi < 4; ++mi) {
                int r = wr * 64 + mi * 16 + (lane & 15);
                af[mi] = *(const short8*)&Al4[r * 8 + (kc ^ (r & 7))];
            }
            #pragma unroll
            for (int ni = 0; ni < 4; ++ni) {
                int r = wc * 64 + ni * 16 + (lane & 15);
                bfr[ni] = *(const short8*)&Bl4[r * 8 + (kc ^ (r & 7))];
            }
            #pragma unroll
            for (int mi = 0; mi < 4; ++mi)
                #pragma unroll
                for (int ni = 0; ni < 4; ++ni)
                    acc[mi][ni] = __builtin_amdgcn_mfma_f32_16x16x32_bf16(
                        af[mi], bfr[ni], acc[mi][ni], 0, 0, 0);
        }
        __syncthreads();
    }

    #pragma unroll
    for (int ni = 0; ni < 4; ++ni) {
        int d = n0 + wc * 64 + ni * 16 + (lane & 15);
        float bv = bias[d];
        #pragma unroll
        for (int mi = 0; mi < 4; ++mi) {
            #pragma unroll
            for (int r = 0; r < 4; ++r) {
                int m = m0 + wr * 64 + mi * 16 + (lane >> 4) * 4 + r;
                int img = m >> 7, t = m & 127;
                int bb = img / 100, nn = img - bb * 100;
                long ob = (((long)bb * T_DIM + t) * N_DIM + nn) * D_DIM + d;
                out[ob] = acc[mi][ni][r] + bv;
            }
        }
    }
}

extern "C" void kernel_launch(void* const* d_in, const int* in_sizes, int n_in,
                              void* d_out, int out_size, void* d_ws, size_t ws_size,
                              hipStream_t stream)
{
    const float* x = (const float*)d_in[0];
    const float* w0 = (const float*)d_in[2];  const float* b0 = (const float*)d_in[3];
    const float* w1 = (const float*)d_in[4];  const float* b1 = (const float*)d_in[5];
    const float* w2 = (const float*)d_in[6];  const float* b2 = (const float*)d_in[7];
    const float* w3 = (const float*)d_in[8];  const float* b3 = (const float*)d_in[9];
    const float* w4 = (const float*)d_in[10]; const float* b4 = (const float*)d_in[11];
    const float* w5 = (const float*)d_in[12]; const float* b5 = (const float*)d_in[13];
    const float* out_w = (const float*)d_in[14];
    const float* out_b = (const float*)d_in[15];
    float* ws = (float*)d_ws;
    float* outp = (float*)d_out;

    const long S0 = 6553600, S1 = 1638400, S2 = 409600;
    const long RT = 13107200;

    float* pLH[3] = { ws,               ws + 3 * S0,           ws + 3 * S0 + 3 * S1 };
    float* pHL[3] = { ws + S0,          ws + 3 * S0 + S1,      ws + 3 * S0 + 3 * S1 + S2 };
    float* pHH[3] = { ws + 2 * S0,      ws + 3 * S0 + 2 * S1,  ws + 3 * S0 + 3 * S1 + 2 * S2 };
    float* pLL2 = ws + 3 * S0 + 3 * S1 + 3 * S2;
    float* comb = ws + 3 * S0 + 3 * S1 + 4 * S2;
    float* thr  = comb + 128;
    float* wbf_f = thr + 51200;
    float* LLa  = wbf_f + 32768;
    float* LLb  = LLa + S0;
    float* bufA = LLb + S1;
    float* bufLL = bufA + RT;            // subband scratch + idwt outputs
    ushort_t* wbf = (ushort_t*)wbf_f;
    ushort_t* Abf = (ushort_t*)bufA;     // final idwt output (bf16), 52 MB
    float* idwt_out2 = bufLL;            // 800*32*64
    float* idwt_out1 = bufLL + S2 * 4;   // 800*64*128
    (void)ws_size; (void)in_sizes; (void)n_in; (void)out_size;

    hipLaunchKernelGGL(k_build_comb, dim3(1), dim3(128), 0, stream,
                       w0, w1, w2, w3, w4, w5, b0, b1, b2, b3, b4, b5, comb);
    hipLaunchKernelGGL(k_cvt_bf16, dim3(256), dim3(256), 0, stream, out_w, wbf, 65536);

    float thr_scale = (float)(sqrt(2.0 * log(128.0)) / 0.6745);

    int Hs[3] = {128, 64, 32}, Ws3[3] = {256, 128, 64};
    const float* curLL = x;
    float* convLLout[3] = { LLa, LLb, pLL2 };

    for (int lev = 0; lev < 3; ++lev) {
        int H = Hs[lev], W = Ws3[lev], h = H >> 1, w = W >> 1;
        long S = (long)NIMG * h * w;
        float* rLL = bufLL;
        float* rLH = bufLL + S;
        float* rHL = bufLL + 2 * S;
        float* rHH = bufLL + 3 * S;
        int nrb = h / 16, nstrips = w / 32;
        if (nrb < 1) nrb = 1;
        if (nstrips < 1) nstrips = 1;
        hipLaunchKernelGGL(k_dwt2d_v3, dim3(NIMG * nrb * nstrips), dim3(256), 0, stream,
                           curLL, rLL, rLH, rHL, rHH,
                           H, W, nrb, nstrips, lev == 0 ? 1 : 0);
        long rows = (long)NIMG * h;
        if (lev == 0) {
            hipLaunchKernelGGL(k_med_v2<128>, dim3((int)(rows / 2)), dim3(256), 0, stream,
                               rHH, thr, thr_scale);
            hipLaunchKernelGGL(k_incept_v8, dim3(NIMG * 4 * 2), dim3(256), 0, stream,
                               rLL, thr, comb, convLLout[lev], pLH[lev], pHL[lev], pHH[lev]);
        } else if (lev == 1) {
            hipLaunchKernelGGL(k_med_v2<64>, dim3((int)(rows / 4)), dim3(256), 0, stream,
                               rHH, thr, thr_scale);
            hipLaunchKernelGGL((k_incept_v7<64, 32, 4, 2>), dim3(NIMG * 4), dim3(256), 0, stream,
                               rLL, thr, comb, convLLout[lev], pLH[lev], pHL[lev], pHH[lev]);
        } else {
            hipLaunchKernelGGL(k_med_v2<32>, dim3((int)(rows / 8)), dim3(256), 0, stream,
                               rHH, thr, thr_scale);
            hipLaunchKernelGGL((k_incept_v7<32, 16, 1, 2>), dim3(NIMG * 4), dim3(256), 0, stream,
                               rLL, thr, comb, convLLout[lev], pLH[lev], pHL[lev], pHH[lev]);
        }
        curLL = convLLout[lev];
    }

    // iDWT chain (fused, v4: 32-row tiles + XCD swizzle)
    hipLaunchKernelGGL(k_idwt2d_v4, dim3(NIMG * 1 * 1), dim3(256), 0, stream,
                       pLL2, pLH[2], pHL[2], pHH[2], idwt_out2, (ushort_t*)0,
                       32, 64, 1, 1, 0);
    hipLaunchKernelGGL(k_idwt2d_v4, dim3(NIMG * 2 * 2), dim3(256), 0, stream,
                       idwt_out2, pLH[1], pHL[1], pHH[1], idwt_out1, (ushort_t*)0,
                       64, 128, 2, 2, 0);
    hipLaunchKernelGGL(k_idwt2d_v4, dim3(NIMG * 4 * 4), dim3(256), 0, stream,
                       idwt_out1, pLH[0], pHL[0], pHH[0], (float*)0, Abf,
                       128, 256, 4, 4, 1);

    dim3 gg(102400 / 128, 2);
    hipLaunchKernelGGL(k_gemm_bf16, gg, dim3(256), 0, stream, Abf, wbf, out_b, outp);
}

// Round 20
// 399.133 us; speedup vs baseline: 1.2407x; 1.0177x over previous
//
#include <hip/hip_runtime.h>
#include <math.h>

#define NIMG 800
#define T_DIM 128
#define N_DIM 100
#define D_DIM 256

typedef unsigned short ushort_t;
typedef unsigned int uint_t;
typedef __attribute__((ext_vector_type(8))) short short8;
typedef __attribute__((ext_vector_type(4))) float f32x4;

// REC_LO[t] = DEC_LO[15-t];  REC_HI[t] = DEC_LO[t] * (-1)^t
__constant__ float c_RL[16] = {
     0.05441584224308161,   0.3128715909144659,    0.6756307362980128,    0.5853546836548691,
    -0.015829105256023893, -0.2840155429624281,    0.00047248457399797254,0.128747426620186,
    -0.01736930100202211,  -0.04408825393106472,   0.013981027917015516,  0.008746094047015655,
    -0.00487035299301066,  -0.0003917403729959771, 0.0006754494059985568, -0.00011747678400228192
};
__constant__ float c_RH[16] = {
    -0.00011747678400228192,-0.0006754494059985568,-0.0003917403729959771, 0.00487035299301066,
     0.008746094047015655,  -0.013981027917015516, -0.04408825393106472,   0.01736930100202211,
     0.128747426620186,     -0.00047248457399797254,-0.2840155429624281,   0.015829105256023893,
     0.5853546836548691,    -0.6756307362980128,    0.3128715909144659,   -0.05441584224308161
};

__device__ inline ushort_t f2bf(float f) {
    uint_t u = __float_as_uint(f);
    uint_t r = (u + 0x7FFFu + ((u >> 16) & 1u)) >> 16;
    return (ushort_t)r;
}

__device__ inline float softthr(float x, float th) {
    float m = fabsf(x) - th;
    return (m > 0.f) ? copysignf(m, x) : 0.f;
}

// Build combined 11x11 inception kernel
__global__ void k_build_comb(const float* w0, const float* w1, const float* w2,
                             const float* w3, const float* w4, const float* w5,
                             const float* b0, const float* b1, const float* b2,
                             const float* b3, const float* b4, const float* b5,
                             float* comb)
{
    int t = threadIdx.x;
    const float* wp[6] = {w0, w1, w2, w3, w4, w5};
    if (t < 121) {
        int dy = t / 11 - 5, dx = t % 11 - 5;
        int ay = dy < 0 ? -dy : dy, ax = dx < 0 ? -dx : dx;
        int a = ay > ax ? ay : ax;
        float s = 0.f;
        for (int i = a; i < 6; ++i) {
            int k = 2 * i + 1;
            s += wp[i][(i + dy) * k + (i + dx)];
        }
        comb[t] = s * (1.0f / 6.0f);
    } else if (t == 121) {
        comb[121] = (b0[0] + b1[0] + b2[0] + b3[0] + b4[0] + b5[0]) * (1.0f / 6.0f);
    }
}

__global__ void k_cvt_bf16(const float* __restrict__ in, ushort_t* __restrict__ out, int n)
{
    int i = blockIdx.x * blockDim.x + threadIdx.x;
    if (i < n) out[i] = f2bf(in[i]);
}

// Fused per-level 2D DWT v3: register-tiled passes, float4 staging, XCD swizzle.
__global__ __launch_bounds__(256) void k_dwt2d_v3(const float* __restrict__ in,
    float* __restrict__ LL, float* __restrict__ LH,
    float* __restrict__ HL, float* __restrict__ HH,
    int H, int W, int nrb, int nstrips, int level0)
{
    __shared__ float xs[46 * 80];
    __shared__ float LpB[2 * 688];
    __shared__ float HpB[2 * 688];
    int h = H >> 1, w = W >> 1;
    int cpx = gridDim.x >> 3;
    int b0i = blockIdx.x;
    int bid = (b0i & 7) * cpx + (b0i >> 3);
    int per = nrb * nstrips;
    int img = bid / per;
    int rem = bid - img * per;
    int rb = rem / nstrips;
    int q = rem - rb * nstrips;
    int r0 = rb * 16, q0 = q * 32;
    int cb = 2 * q0 - 8;
    int jbase = 2 * r0 - 7;
    int tid = threadIdx.x;

    const float* ip; long rstride;
    if (level0) {
        int bb = img / 100, nn = img - bb * 100;
        ip = in + (long)bb * (T_DIM * N_DIM * D_DIM) + (long)nn * D_DIM;
        rstride = (long)N_DIM * D_DIM;
    } else {
        ip = in + (long)img * H * W;
        rstride = W;
    }

    for (int s = tid; s < 46 * 20; s += 256) {
        int jl = s / 20, k = s - jl * 20;
        int gj = jbase + jl, gc = cb + 4 * k;
        float4 v = make_float4(0.f, 0.f, 0.f, 0.f);
        if (gj >= 0 && gj < H && gc >= 0 && gc < W)
            v = *(const float4*)&ip[(long)gj * rstride + gc];
        *(float4*)&xs[jl * 80 + 4 * k] = v;
    }
    __syncthreads();

    for (int s = tid; s < 320; s += 256) {
        int g = s / 80, c = s - g * 80;
        float xv[22];
        const float* bp = xs + (8 * g) * 80 + c;
        #pragma unroll
        for (int k = 0; k < 22; ++k) xv[k] = bp[k * 80];
        #pragma unroll
        for (int o = 0; o < 4; ++o) {
            float sl = 0.f, sh = 0.f;
            #pragma unroll
            for (int t = 0; t < 16; ++t) {
                float v = xv[2 * o + t];
                sl = fmaf(c_RL[t], v, sl);
                sh = fmaf(c_RH[t], v, sh);
            }
            int il = 4 * g + o;
            int a = (c & 1) * 688 + il * 41 + (c >> 1);
            LpB[a] = sl;
            HpB[a] = sh;
        }
    }
    __syncthreads();

    {
        int rl = tid >> 4;
        int cp = tid & 15;
        int cl = cp * 2;
        float Lp0[10], Lp1[10], Hp0[10], Hp1[10];
        int base = rl * 41 + cl;
        #pragma unroll
        for (int k = 0; k < 10; ++k) {
            Lp0[k] = LpB[base + k];
            Lp1[k] = LpB[688 + base + k];
            Hp0[k] = HpB[base + k];
            Hp1[k] = HpB[688 + base + k];
        }
        float rll[2], rlh[2], rhl[2], rhh[2];
        #pragma unroll
        for (int n = 0; n < 2; ++n) {
            float ll = 0.f, lh = 0.f, hl = 0.f, hh = 0.f;
            #pragma unroll
            for (int t = 0; t < 16; ++t) {
                const int p = (t + 1) & 1;
                const int k = n + ((t + 1) >> 1);
                float av = p ? Lp1[k] : Lp0[k];
                float bv = p ? Hp1[k] : Hp0[k];
                ll = fmaf(c_RL[t], av, ll);
                lh = fmaf(c_RH[t], av, lh);
                hl = fmaf(c_RL[t], bv, hl);
                hh = fmaf(c_RH[t], bv, hh);
            }
            rll[n] = ll; rlh[n] = lh; rhl[n] = hl; rhh[n] = hh;
        }
        long o = (long)img * h * w + (long)(r0 + rl) * w + (q0 + cl);
        *(float2*)&LL[o] = make_float2(rll[0], rll[1]);
        *(float2*)&LH[o] = make_float2(rlh[0], rlh[1]);
        *(float2*)&HL[o] = make_float2(rhl[0], rhl[1]);
        *(float2*)&HH[o] = make_float2(rhh[0], rhh[1]);
    }
}

// Fused per-level 2D iDWT v4: 32-out-row tiles, float4 staging, XCD swizzle.
__global__ __launch_bounds__(256) void k_idwt2d_v4(const float* __restrict__ LLp,
    const float* __restrict__ LHp, const float* __restrict__ HLp,
    const float* __restrict__ HHp, float* __restrict__ outp,
    ushort_t* __restrict__ outbf, int H, int W, int nrb, int nstrips, int fin)
{
    __shared__ float subf[4][24][41];
    __shared__ float sLm[24 * 64];
    __shared__ float sHm[24 * 64];
    int h = H >> 1, w = W >> 1;
    int cpx = gridDim.x >> 3;
    int b0i = blockIdx.x;
    int bid = (b0i & 7) * cpx + (b0i >> 3);
    int per = nrb * nstrips;
    int img = bid / per;
    int rem = bid - img * per;
    int rb = rem / nstrips;
    int qs = rem - rb * nstrips;
    int j0 = rb * 32, q0 = qs * 64;
    int rbase = (j0 >> 1) - 4;
    int i0 = (q0 >> 1) - 4;
    int tid = threadIdx.x;
    long ibase = (long)img * h * w;

    for (int s = tid; s < 4 * 24 * 10; s += 256) {
        int b = s / 240;
        int r2 = s - b * 240;
        int r = r2 / 10, c4 = r2 - r * 10;
        int gr = rbase + r, gc = i0 + 4 * c4;
        float4 v = make_float4(0.f, 0.f, 0.f, 0.f);
        if (gr >= 0 && gr < h && gc >= 0 && gc < w) {
            const float* p = (b == 0) ? LLp : (b == 1) ? LHp : (b == 2) ? HLp : HHp;
            v = *(const float4*)&p[ibase + (long)gr * w + gc];
        }
        subf[b][r][4 * c4]     = v.x;
        subf[b][r][4 * c4 + 1] = v.y;
        subf[b][r][4 * c4 + 2] = v.z;
        subf[b][r][4 * c4 + 3] = v.w;
    }
    __syncthreads();

    for (int s = tid; s < 24 * 16; s += 256) {
        int r = s >> 4;
        int cg = s & 15;
        int lcb = cg * 2;
        float rs[4][10];
        #pragma unroll
        for (int b = 0; b < 4; ++b)
            #pragma unroll
            for (int k = 0; k < 10; ++k)
                rs[b][k] = subf[b][r][lcb + k];
        float accL[4], accH[4];
        #pragma unroll
        for (int n = 0; n < 4; ++n) {
            const int t0 = (n & 1) ? 0 : 1;
            const int kb = ((n & 1) ? 8 : 7) + (n >> 1);
            float aL = 0.f, aH = 0.f;
            #pragma unroll
            for (int tt = 0; tt < 8; ++tt) {
                const int t = t0 + 2 * tt;
                const int k = kb - tt;
                aL = fmaf(c_RL[t], rs[0][k], aL);
                aL = fmaf(c_RH[t], rs[1][k], aL);
                aH = fmaf(c_RL[t], rs[2][k], aH);
                aH = fmaf(c_RH[t], rs[3][k], aH);
            }
            accL[n] = aL; accH[n] = aH;
        }
        *(float4*)&sLm[r * 64 + cg * 4] = make_float4(accL[0], accL[1], accL[2], accL[3]);
        *(float4*)&sHm[r * 64 + cg * 4] = make_float4(accH[0], accH[1], accH[2], accH[3]);
    }
    __syncthreads();

    {
        int g = tid >> 6;
        int cl = tid & 63;
        float rL[12], rH[12];
        #pragma unroll
        for (int k = 0; k < 12; ++k) {
            rL[k] = sLm[(4 * g + k) * 64 + cl];
            rH[k] = sHm[(4 * g + k) * 64 + cl];
        }
        #pragma unroll
        for (int m = 0; m < 8; ++m) {
            const int t0 = (m & 1) ? 0 : 1;
            const int kb = ((m & 1) ? 8 : 7) + (m >> 1);
            float v = 0.f;
            #pragma unroll
            for (int tt = 0; tt < 8; ++tt) {
                const int t = t0 + 2 * tt;
                const int k = kb - tt;
                v = fmaf(c_RL[t], rL[k], v);
                v = fmaf(c_RH[t], rH[k], v);
            }
            int j = j0 + g * 8 + m;
            long o = (long)img * H * W + (long)j * W + q0 + cl;
            if (fin) outbf[o] = f2bf(v);
            else outp[o] = v;
        }
    }
}

// Bitonic-sort row median of |HH| (exact).
template<int W>
__global__ __launch_bounds__(256) void k_med_v2(const float* __restrict__ HH,
    float* __restrict__ thr, float scale)
{
    constexpr int R = 256 / W;
    __shared__ float smv[256];
    int tid = threadIdx.x;
    int l = tid % W;
    long row = (long)blockIdx.x * R + tid / W;
    float v = fabsf(HH[row * W + l]);
    #pragma unroll
    for (int k = 2; k <= W; k <<= 1) {
        #pragma unroll
        for (int j = k >> 1; j > 0; j >>= 1) {
            float pv;
            if (j < 64) {
                pv = __shfl_xor(v, j, 64);
            } else {
                smv[tid] = v;
                __syncthreads();
                pv = smv[tid ^ j];
                __syncthreads();
            }
            bool keepmin = ((l & k) == 0) == ((l & j) == 0);
            v = keepmin ? fminf(v, pv) : fmaxf(v, pv);
        }
    }
    if (l == (W - 1) / 2) thr[row] = v * scale;
}

// Register conv v8 family: mod-4 column-split LDS, conflict-free, XCD swizzle,
// fused per-row soft-threshold on staging (tmul=0 for LL band -> identity).
// Templated on image geometry: WT width, BLK threads; tile = BH out rows.
// QS = WT/4 quarters, QP = QS+5 pitch (odd), TR = BH+10.
#define PICK(d) ( (d)==-5 ? f3[0] : (d)==-4 ? f0[0] : (d)==-3 ? f1[0] : \
                  (d)==-2 ? f2[0] : (d)==-1 ? f3[1] : (d)==0  ? f0[1] : \
                  (d)==1  ? f1[1] : (d)==2  ? f2[1] : (d)==3  ? f3[2] : \
                  (d)==4  ? f0[2] : (d)==5  ? f1[2] : (d)==6  ? f2[2] : \
                  (d)==7  ? f3[3] : f0[3] )
template<int WT, int BH, int BLK>
__global__ __launch_bounds__(BLK) void k_incept_v8t(const float* __restrict__ bands,
    const float* __restrict__ thrp, const float* __restrict__ comb,
    float* __restrict__ oLL, float* __restrict__ oLH,
    float* __restrict__ oHL, float* __restrict__ oHH)
{
    constexpr int Himg = WT / 2;          // image height
    constexpr int NRB = Himg / BH;        // row-bands per image
    constexpr int QS = WT / 4;            // quarters per row
    constexpr int QP = QS + 5;            // staged quarters (2 pad each side) + 1
    constexpr int TR = BH + 10;
    constexpr int AS = TR * QP + 2;
    __shared__ float sm4[4 * AS];

    int cpx = gridDim.x >> 3;
    int b0i = blockIdx.x;
    int bid = (b0i & 7) * cpx + (b0i >> 3);
    int rb = (NRB > 1) ? (bid & (NRB - 1)) : 0;
    int bi = (NRB > 1) ? (bid >> 1) : bid;
    int band = bi & 3;
    int img = bi >> 2;
    long S = (long)NIMG * Himg * WT;
    const float* in = bands + (long)band * S + (long)img * (Himg * WT);
    float* outp = (band == 0 ? oLL : band == 1 ? oLH : band == 2 ? oHL : oHH)
                  + (long)img * (Himg * WT);
    float tmul = (band == 0) ? 0.f : 1.f;
    const float* trow = thrp + (long)img * Himg;
    int r0 = rb * BH;
    int tid = threadIdx.x;

    for (int s = tid; s < TR * (QS + 4); s += BLK) {
        int r = s / (QS + 4), qi = s - r * (QS + 4);
        int q = qi - 2;
        int gr = r0 - 5 + r;
        float4 v = make_float4(0.f, 0.f, 0.f, 0.f);
        if (gr >= 0 && gr < Himg && q >= 0 && q < QS) {
            v = *(const float4*)&in[(long)gr * WT + 4 * q];
            float th = tmul * trow[gr];
            v.x = softthr(v.x, th);
            v.y = softthr(v.y, th);
            v.z = softthr(v.z, th);
            v.w = softthr(v.w, th);
        }
        int a = r * QP + ((TR > 42 || QP == 37) ? 0 : ((r >> 2) & 1)) + qi;
        // L0 (QP=37) uses plain layout (matches proven v8); others stagger rows
        sm4[0 * AS + a] = v.x;
        sm4[1 * AS + a] = v.y;
        sm4[2 * AS + a] = v.z;
        sm4[3 * AS + a] = v.w;
    }
    __syncthreads();

    int cq = tid & (QS - 1);
    int rg = tid / QS;
    float cb = comb[121];

    float acc[4][4];
    #pragma unroll
    for (int o = 0; o < 4; ++o)
        #pragma unroll
        for (int n = 0; n < 4; ++n) acc[o][n] = 0.f;

    #pragma unroll
    for (int i = 0; i < 14; ++i) {
        int tr = rg * 4 + i;
        int base = tr * QP + ((TR > 42 || QP == 37) ? 0 : ((tr >> 2) & 1)) + cq + 2;
        float f0[4], f1[3], f2[3], f3[4];
        f3[0] = sm4[3 * AS + base - 2];
        f0[0] = sm4[0 * AS + base - 1];
        f1[0] = sm4[1 * AS + base - 1];
        f2[0] = sm4[2 * AS + base - 1];
        f3[1] = sm4[3 * AS + base - 1];
        f0[1] = sm4[0 * AS + base];
        f1[1] = sm4[1 * AS + base];
        f2[1] = sm4[2 * AS + base];
        f3[2] = sm4[3 * AS + base];
        f0[2] = sm4[0 * AS + base + 1];
        f1[2] = sm4[1 * AS + base + 1];
        f2[2] = sm4[2 * AS + base + 1];
        f3[3] = sm4[3 * AS + base + 1];
        f0[3] = sm4[0 * AS + base + 2];
        #pragma unroll
        for (int ky = 0; ky < 11; ++ky) {
            const int o = i - ky;
            if (o >= 0 && o < 4) {
                #pragma unroll
                for (int kx = 0; kx < 11; ++kx) {
                    float cw = comb[ky * 11 + kx];
                    #pragma unroll
                    for (int n = 0; n < 4; ++n) {
                        const int d = n + kx - 5;
                        acc[o][n] = fmaf(PICK(d), cw, acc[o][n]);
                    }
                }
            }
        }
    }

    #pragma unroll
    for (int o = 0; o < 4; ++o) {
        int oy = r0 + rg * 4 + o;
        float4 st = make_float4(acc[o][0] + cb, acc[o][1] + cb,
                                acc[o][2] + cb, acc[o][3] + cb);
        *(float4*)&outp[(long)oy * WT + 4 * cq] = st;
    }
}

// Register conv v7 (L2), fused soft-threshold on staging.
template<int WT, int BH, int OC, int NC>
__global__ __launch_bounds__(256) void k_incept_v7(const float* __restrict__ bands,
    const float* __restrict__ thrp, const float* __restrict__ comb,
    float* __restrict__ oLL, float* __restrict__ oLH,
    float* __restrict__ oHL, float* __restrict__ oHH)
{
    constexpr int Himg = WT / 2;
    constexpr int NRB = Himg / BH;
    constexpr int LW = WT / 2 + 6;
    constexpr int PITCH = WT / 2 + 7;
    constexpr int TR = BH + 10;
    constexpr int NB = WT / NC;
    __shared__ float smE[TR * PITCH + 1];
    __shared__ float smO[TR * PITCH + 1];

    int bid = blockIdx.x;
    int rb = (NRB > 1) ? (bid % NRB) : 0;
    int bi = (NRB > 1) ? (bid / NRB) : bid;
    int band = bi & 3;
    int img = bi >> 2;
    long S = (long)NIMG * Himg * WT;
    const float* in = bands + (long)band * S + (long)img * Himg * WT;
    float* outp = (band == 0 ? oLL : band == 1 ? oLH : band == 2 ? oHL : oHH)
                  + (long)img * Himg * WT;
    float tmul = (band == 0) ? 0.f : 1.f;
    const float* trow = thrp + (long)img * Himg;
    int r0 = rb * BH;
    int tid = threadIdx.x;

    for (int s = tid; s < TR * LW; s += 256) {
        int r = s / LW, j = s - r * LW;
        int c = j - 3;
        int gr = r0 - 5 + r;
        float2 v = make_float2(0.f, 0.f);
        if (gr >= 0 && gr < Himg && c >= 0 && c < WT / 2) {
            v = *(const float2*)&in[(long)gr * WT + 2 * c];
            float th = tmul * trow[gr];
            v.x = softthr(v.x, th);
            v.y = softthr(v.y, th);
        }
        int a = r * PITCH + ((r >> 2) & 1) + j;
        smE[a] = v.x;
        smO[a] = v.y;
    }
    __syncthreads();

    int cq = tid % NB;
    int rg = tid / NB;
    int x0 = cq * NC;
    float cb = comb[121];

    float acc[OC][NC];
    #pragma unroll
    for (int o = 0; o < OC; ++o)
        #pragma unroll
        for (int n = 0; n < NC; ++n) acc[o][n] = 0.f;

    float bufE[NC / 2 + 5], bufO[NC / 2 + 5];

    #pragma unroll
    for (int i = 0; i < OC + 10; ++i) {
        int tr = rg * OC + i;
        int base = tr * PITCH + ((tr >> 2) & 1) + (x0 >> 1);
        #pragma unroll
        for (int j = 0; j < NC / 2 + 5; ++j) {
            bufE[j] = smE[base + j + 1];
            bufO[j] = smO[base + j];
        }
        #pragma unroll
        for (int ky = 0; ky < 11; ++ky) {
            const int o = i - ky;
            if (o >= 0 && o < OC) {
                #pragma unroll
                for (int kx = 0; kx < 11; ++kx) {
                    float cw = comb[ky * 11 + kx];
                    #pragma unroll
                    for (int n = 0; n < NC; ++n) {
                        const int d = n + kx - 5;
                        float v = ((d & 1) == 0) ? bufE[(d + 4) / 2] : bufO[(d + 5) / 2];
                        acc[o][n] = fmaf(v, cw, acc[o][n]);
                    }
                }
            }
        }
    }

    #pragma unroll
    for (int o = 0; o < OC; ++o) {
        int oy = r0 + rg * OC + o;
        float2 st = make_float2(acc[o][0] + cb, acc[o][1] + cb);
        *(float2*)&outp[(long)oy * WT + x0] = st;
    }
}

// bf16 MFMA GEMM: out[m,d] = sum_k A[m,k]*W[d,k] + bias[d], scattered output.
__global__ __launch_bounds__(256) void k_gemm_bf16(const ushort_t* __restrict__ A,
    const ushort_t* __restrict__ Bw, const float* __restrict__ bias,
    float* __restrict__ out)
{
    __shared__ uint4 Al4[128 * 8];
    __shared__ uint4 Bl4[128 * 8];
    int m0 = blockIdx.x * 128, n0 = blockIdx.y * 128;
    int tid = threadIdx.x;
    int wid = tid >> 6, lane = tid & 63;
    int wr = wid >> 1, wc = wid & 1;
    f32x4 acc[4][4];
    #pragma unroll
    for (int a = 0; a < 4; ++a)
        #pragma unroll
        for (int b = 0; b < 4; ++b)
            acc[a][b] = (f32x4){0.f, 0.f, 0.f, 0.f};

    const uint4* Ag = (const uint4*)A;
    const uint4* Bg = (const uint4*)Bw;
    int row = tid >> 1, half = tid & 1;

    for (int k0 = 0; k0 < 256; k0 += 64) {
        int gca = ((m0 + row) * 256 + k0 + half * 32) >> 3;
        int gcb = ((n0 + row) * 256 + k0 + half * 32) >> 3;
        #pragma unroll
        for (int q = 0; q < 4; ++q) {
            int c = half * 4 + q;
            int sw = c ^ (row & 7);
            Al4[row * 8 + sw] = Ag[gca + q];
            Bl4[row * 8 + sw] = Bg[gcb + q];
        }
        __syncthreads();
        #pragma unroll
        for (int ks = 0; ks < 2; ++ks) {
            short8 af[4], bfr[4];
            int kc = ks * 4 + (lane >> 4);
            #pragma unroll
            for (int mi = 0; mi < 4; ++mi) {
                int r = wr * 64 + mi * 16 + (lane & 15);
                af[mi] = *(const short8*)&Al4[r * 8 + (kc ^ (r & 7))];
            }
            #pragma unroll
            for (int ni = 0; ni < 4; ++ni) {
                int r = wc * 64 + ni * 16 + (lane & 15);
                bfr[ni] = *(const short8*)&Bl4[r * 8 + (kc ^ (r & 7))];
            }
            #pragma unroll
            for (int mi = 0; mi < 4; ++mi)
                #pragma unroll
                for (int ni = 0; ni < 4; ++ni)
                    acc[mi][ni] = __builtin_amdgcn_mfma_f32_16x16x32_bf16(
                        af[mi], bfr[ni], acc[mi][ni], 0, 0, 0);
        }
        __syncthreads();
    }

    #pragma unroll
    for (int ni = 0; ni < 4; ++ni) {
        int d = n0 + wc * 64 + ni * 16 + (lane & 15);
        float bv = bias[d];
        #pragma unroll
        for (int mi = 0; mi < 4; ++mi) {
            #pragma unroll
            for (int r = 0; r < 4; ++r) {
                int m = m0 + wr * 64 + mi * 16 + (lane >> 4) * 4 + r;
                int img = m >> 7, t = m & 127;
                int bb = img / 100, nn = img - bb * 100;
                long ob = (((long)bb * T_DIM + t) * N_DIM + nn) * D_DIM + d;
                out[ob] = acc[mi][ni][r] + bv;
            }
        }
    }
}

extern "C" void kernel_launch(void* const* d_in, const int* in_sizes, int n_in,
                              void* d_out, int out_size, void* d_ws, size_t ws_size,
                              hipStream_t stream)
{
    const float* x = (const float*)d_in[0];
    const float* w0 = (const float*)d_in[2];  const float* b0 = (const float*)d_in[3];
    const float* w1 = (const float*)d_in[4];  const float* b1 = (const float*)d_in[5];
    const float* w2 = (const float*)d_in[6];  const float* b2 = (const float*)d_in[7];
    const float* w3 = (const float*)d_in[8];  const float* b3 = (const float*)d_in[9];
    const float* w4 = (const float*)d_in[10]; const float* b4 = (const float*)d_in[11];
    const float* w5 = (const float*)d_in[12]; const float* b5 = (const float*)d_in[13];
    const float* out_w = (const float*)d_in[14];
    const float* out_b = (const float*)d_in[15];
    float* ws = (float*)d_ws;
    float* outp = (float*)d_out;

    const long S0 = 6553600, S1 = 1638400, S2 = 409600;
    const long RT = 13107200;

    float* pLH[3] = { ws,               ws + 3 * S0,           ws + 3 * S0 + 3 * S1 };
    float* pHL[3] = { ws + S0,          ws + 3 * S0 + S1,      ws + 3 * S0 + 3 * S1 + S2 };
    float* pHH[3] = { ws + 2 * S0,      ws + 3 * S0 + 2 * S1,  ws + 3 * S0 + 3 * S1 + 2 * S2 };
    float* pLL2 = ws + 3 * S0 + 3 * S1 + 3 * S2;
    float* comb = ws + 3 * S0 + 3 * S1 + 4 * S2;
    float* thr  = comb + 128;
    float* wbf_f = thr + 51200;
    float* LLa  = wbf_f + 32768;
    float* LLb  = LLa + S0;
    float* bufA = LLb + S1;
    float* bufLL = bufA + RT;            // subband scratch + idwt outputs
    ushort_t* wbf = (ushort_t*)wbf_f;
    ushort_t* Abf = (ushort_t*)bufA;     // final idwt output (bf16), 52 MB
    float* idwt_out2 = bufLL;            // 800*32*64
    float* idwt_out1 = bufLL + S2 * 4;   // 800*64*128
    (void)ws_size; (void)in_sizes; (void)n_in; (void)out_size;

    hipLaunchKernelGGL(k_build_comb, dim3(1), dim3(128), 0, stream,
                       w0, w1, w2, w3, w4, w5, b0, b1, b2, b3, b4, b5, comb);
    hipLaunchKernelGGL(k_cvt_bf16, dim3(256), dim3(256), 0, stream, out_w, wbf, 65536);

    float thr_scale = (float)(sqrt(2.0 * log(128.0)) / 0.6745);

    int Hs[3] = {128, 64, 32}, Ws3[3] = {256, 128, 64};
    const float* curLL = x;
    float* convLLout[3] = { LLa, LLb, pLL2 };

    for (int lev = 0; lev < 3; ++lev) {
        int H = Hs[lev], W = Ws3[lev], h = H >> 1, w = W >> 1;
        long S = (long)NIMG * h * w;
        float* rLL = bufLL;
        float* rLH = bufLL + S;
        float* rHL = bufLL + 2 * S;
        float* rHH = bufLL + 3 * S;
        int nrb = h / 16, nstrips = w / 32;
        if (nrb < 1) nrb = 1;
        if (nstrips < 1) nstrips = 1;
        hipLaunchKernelGGL(k_dwt2d_v3, dim3(NIMG * nrb * nstrips), dim3(256), 0, stream,
                           curLL, rLL, rLH, rHL, rHH,
                           H, W, nrb, nstrips, lev == 0 ? 1 : 0);
        long rows = (long)NIMG * h;
        if (lev == 0) {
            hipLaunchKernelGGL(k_med_v2<128>, dim3((int)(rows / 2)), dim3(256), 0, stream,
                               rHH, thr, thr_scale);
            hipLaunchKernelGGL((k_incept_v8t<128, 32, 256>), dim3(NIMG * 4 * 2), dim3(256), 0, stream,
                               rLL, thr, comb, convLLout[lev], pLH[lev], pHL[lev], pHH[lev]);
        } else if (lev == 1) {
            hipLaunchKernelGGL(k_med_v2<64>, dim3((int)(rows / 4)), dim3(256), 0, stream,
                               rHH, thr, thr_scale);
            hipLaunchKernelGGL((k_incept_v8t<64, 32, 128>), dim3(NIMG * 4), dim3(128), 0, stream,
                               rLL, thr, comb, convLLout[lev], pLH[lev], pHL[lev], pHH[lev]);
        } else {
            hipLaunchKernelGGL(k_med_v2<32>, dim3((int)(rows / 8)), dim3(256), 0, stream,
                               rHH, thr, thr_scale);
            hipLaunchKernelGGL((k_incept_v7<32, 16, 1, 2>), dim3(NIMG * 4), dim3(256), 0, stream,
                               rLL, thr, comb, convLLout[lev], pLH[lev], pHL[lev], pHH[lev]);
        }
        curLL = convLLout[lev];
    }

    // iDWT chain (fused, v4: 32-row tiles + XCD swizzle)
    hipLaunchKernelGGL(k_idwt2d_v4, dim3(NIMG * 1 * 1), dim3(256), 0, stream,
                       pLL2, pLH[2], pHL[2], pHH[2], idwt_out2, (ushort_t*)0,
                       32, 64, 1, 1, 0);
    hipLaunchKernelGGL(k_idwt2d_v4, dim3(NIMG * 2 * 2), dim3(256), 0, stream,
                       idwt_out2, pLH[1], pHL[1], pHH[1], idwt_out1, (ushort_t*)0,
                       64, 128, 2, 2, 0);
    hipLaunchKernelGGL(k_idwt2d_v4, dim3(NIMG * 4 * 4), dim3(256), 0, stream,
                       idwt_out1, pLH[0], pHL[0], pHH[0], (float*)0, Abf,
                       128, 256, 4, 4, 1);

    dim3 gg(102400 / 128, 2);
    hipLaunchKernelGGL(k_gemm_bf16, gg, dim3(256), 0, stream, Abf, wbf, out_b, outp);
}